// Round 2
// baseline (58916.205 us; speedup 1.0000x reference)
//
#include <hip/hip_runtime.h>
#include <math.h>

#define NN 2500
#define EE 50000
#define CC 128
#define LL 25
#define HH 8
#define AA 64
#define VV 16
#define FF 128
#define NBASIS 600
#define EFD (NBASIS + 2*CC)   // 856

__device__ __forceinline__ float silu_f(float x){ return x / (1.0f + expf(-x)); }

__device__ __forceinline__ float getc(const float4& v, int k){
  return k==0 ? v.x : (k==1 ? v.y : (k==2 ? v.z : v.w));
}

__device__ __forceinline__ void fma16(float (&cm)[4][4], const float4& av, const float4& bv){
  cm[0][0]+=av.x*bv.x; cm[0][1]+=av.x*bv.y; cm[0][2]+=av.x*bv.z; cm[0][3]+=av.x*bv.w;
  cm[1][0]+=av.y*bv.x; cm[1][1]+=av.y*bv.y; cm[1][2]+=av.y*bv.z; cm[1][3]+=av.y*bv.w;
  cm[2][0]+=av.z*bv.x; cm[2][1]+=av.z*bv.y; cm[2][2]+=av.z*bv.z; cm[2][3]+=av.z*bv.w;
  cm[3][0]+=av.w*bv.x; cm[3][1]+=av.w*bv.y; cm[3][2]+=av.w*bv.z; cm[3][3]+=av.w*bv.w;
}

// ---------------- edge sort by dst (counting sort) ----------------
__global__ void k_hist(const int* __restrict__ ei, int* __restrict__ counts){
  int e = blockIdx.x*256 + threadIdx.x;
  if (e < EE) atomicAdd(&counts[ei[EE+e]], 1);
}

__global__ void k_scan(const int* __restrict__ counts, int* __restrict__ offsets){
  __shared__ int part[256];
  __shared__ int partx[257];
  int t = threadIdx.x;
  const int chunk = (NN + 255)/256;   // 10
  int base = t*chunk;
  int s = 0;
  for (int i=0;i<chunk;i++){ int idx=base+i; if (idx<NN) s += counts[idx]; }
  part[t] = s;
  __syncthreads();
  if (t==0){ int acc=0; for (int i=0;i<256;i++){ partx[i]=acc; acc+=part[i]; } partx[256]=acc; }
  __syncthreads();
  int acc = partx[t];
  for (int i=0;i<chunk;i++){ int idx=base+i; if (idx<NN){ offsets[idx]=acc; acc+=counts[idx]; } }
  if (t==0) offsets[NN] = partx[256];
}

__global__ void k_scatter(const int* __restrict__ ei, const int* __restrict__ offsets,
                          int* __restrict__ cursor, int* __restrict__ order){
  int e = blockIdx.x*256 + threadIdx.x;
  if (e < EE){
    int d = ei[EE+e];
    int p = atomicAdd(&cursor[d], 1);
    order[offsets[d]+p] = e;
  }
}

// ---------------- init x: only l=0 row populated ----------------
__global__ void k_init_x(const int* __restrict__ zn, const float* __restrict__ atom_emb,
                         float* __restrict__ x){
  int idx = blockIdx.x*256 + threadIdx.x;
  int n = idx / (LL*CC);
  int r = idx - n*(LL*CC);
  float v = 0.0f;
  if (r < CC) v = atom_emb[zn[n]*CC + r];
  x[idx] = v;
}

// ---------------- edge scalar features -> rad0, rad1 ----------------
__global__ __launch_bounds__(256)
void k_edge(const int* __restrict__ ei, const int* __restrict__ zn,
            const float* __restrict__ pos,
            const float* __restrict__ src_emb, const float* __restrict__ dst_emb,
            const float* __restrict__ W_e1, const float* __restrict__ W_e2,
            const float* __restrict__ W_rad,
            float* __restrict__ rad0, float* __restrict__ rad1){
  __shared__ float feat[8][EFD];
  __shared__ float efl[8][CC];
  __shared__ float dist[8];
  int t = threadIdx.x;
  int e0 = blockIdx.x*8;
  if (t < 8){
    int e = e0+t;
    int s = ei[e], d = ei[EE+e];
    float dx = pos[s*3]-pos[d*3], dy = pos[s*3+1]-pos[d*3+1], dz = pos[s*3+2]-pos[d*3+2];
    dist[t] = sqrtf(dx*dx+dy*dy+dz*dz);
  }
  __syncthreads();
  const float step = 12.0f/599.0f;
  const float coeff = -0.5f/((2.0f*step)*(2.0f*step));
  for (int eidx=0; eidx<8; ++eidx){
    int e = e0+eidx;
    int zs = zn[ei[e]], zd = zn[ei[EE+e]];
    float de = dist[eidx];
    for (int k=t;k<EFD;k+=256){
      float v;
      if (k < NBASIS){ float u = de - k*step; v = expf(coeff*u*u); }
      else if (k < NBASIS+CC) v = src_emb[zs*CC + (k-NBASIS)];
      else v = dst_emb[zd*CC + (k-NBASIS-CC)];
      feat[eidx][k] = v;
    }
  }
  __syncthreads();
  int eidx = t>>5;
  int c0 = (t&31)*4;
  float a0=0,a1=0,a2=0,a3=0;
  for (int k=0;k<EFD;k++){
    float f = feat[eidx][k];
    const float4 w = *(const float4*)&W_e1[k*CC + c0];
    a0 += f*w.x; a1 += f*w.y; a2 += f*w.z; a3 += f*w.w;
  }
  efl[eidx][c0]=silu_f(a0); efl[eidx][c0+1]=silu_f(a1); efl[eidx][c0+2]=silu_f(a2); efl[eidx][c0+3]=silu_f(a3);
  __syncthreads();
  a0=a1=a2=a3=0;
  for (int k=0;k<CC;k++){
    float f = efl[eidx][k];
    const float4 w = *(const float4*)&W_e2[k*CC+c0];
    a0 += f*w.x; a1 += f*w.y; a2 += f*w.z; a3 += f*w.w;
  }
  __syncthreads();
  efl[eidx][c0]=silu_f(a0); efl[eidx][c0+1]=silu_f(a1); efl[eidx][c0+2]=silu_f(a2); efl[eidx][c0+3]=silu_f(a3);
  __syncthreads();
  #pragma unroll
  for (int l=0;l<2;l++){
    const float* Wr = W_rad + l*CC*CC;
    float r0=0,r1=0,r2=0,r3=0;
    for (int k=0;k<CC;k++){
      float f = efl[eidx][k];
      const float4 w = *(const float4*)&Wr[k*CC+c0];
      r0+=f*w.x; r1+=f*w.y; r2+=f*w.z; r3+=f*w.w;
    }
    float* out = l ? rad1 : rad0;
    *(float4*)&out[(e0+eidx)*CC + c0] = make_float4(r0,r1,r2,r3);
  }
}

// ---------------- equivariant RMS norm -> h ----------------
__global__ __launch_bounds__(256)
void k_rms(const float* __restrict__ x, const float* __restrict__ gamma, float* __restrict__ h){
  __shared__ float xs[LL][CC];
  __shared__ float ps[2][CC];
  int t = threadIdx.x, n = blockIdx.x;
  const float* xr = x + n*LL*CC;
  {
    float4* xs4 = (float4*)&xs[0][0];
    const float4* x4 = (const float4*)xr;
    for (int i=t;i<LL*CC/4;i+=256) xs4[i]=x4[i];
  }
  __syncthreads();
  int c = t&127, hf = t>>7;
  int r0 = hf?13:0, r1 = hf?LL:13;
  float s=0;
  for (int r=r0;r<r1;r++){ float v = xs[r][c]; s += v*v; }
  ps[hf][c]=s;
  __syncthreads();
  float rn = 1.0f/sqrtf((ps[0][c]+ps[1][c])*(1.0f/(float)LL) + 1e-6f);
  float g = gamma[c]*rn;
  float* hr = h + n*LL*CC;
  for (int r=r0;r<r1;r++) hr[r*CC+c] = xs[r][c]*g;
}

// ---------------- attention logits ----------------
__global__ __launch_bounds__(256)
void k_logits(const int* __restrict__ ei, const float* __restrict__ h,
              const float* __restrict__ rad, const float* __restrict__ wig,
              const float* __restrict__ Wa1, const float* __restrict__ wa2,
              float* __restrict__ logits){
  __shared__ float w0[8][LL];
  __shared__ float m0[8][CC];
  __shared__ float aS[8][HH*AA];
  int t = threadIdx.x;
  int e0 = blockIdx.x*8;
  for (int i=t;i<8*LL;i+=256){
    int eidx = i/LL, j = i - eidx*LL;
    w0[eidx][j] = wig[(e0+eidx)*625 + j];
  }
  __syncthreads();
  {
    int c = t&127, eg = t>>7;
    for (int j=0;j<4;j++){
      int e = e0 + eg*4 + j;
      int s = ei[e], d = ei[EE+e];
      const float* hs = h + s*LL*CC + c;
      const float* hd = h + d*LL*CC + c;
      float acc = 0;
      #pragma unroll
      for (int r=0;r<LL;r++) acc += w0[eg*4+j][r]*(hs[r*CC]+hd[r*CC]);
      m0[eg*4+j][c] = acc*rad[e*CC+c];
    }
  }
  __syncthreads();
  float accA[16];
  #pragma unroll
  for (int i=0;i<16;i++) accA[i]=0;
  for (int k=0;k<CC;k++){
    float wv0 = Wa1[k*512 + t];
    float wv1 = Wa1[k*512 + 256 + t];
    #pragma unroll
    for (int e=0;e<8;e++){
      float mv = m0[e][k];
      accA[e*2]   += mv*wv0;
      accA[e*2+1] += mv*wv1;
    }
  }
  #pragma unroll
  for (int e=0;e<8;e++){ aS[e][t]=silu_f(accA[e*2]); aS[e][256+t]=silu_f(accA[e*2+1]); }
  __syncthreads();
  if (t < 64){
    int eidx = t>>3, hh2 = t&7;
    float lg = 0;
    #pragma unroll
    for (int a=0;a<AA;a++) lg += aS[eidx][hh2*AA+a]*wa2[hh2*AA+a];
    logits[(e0+eidx)*HH + hh2] = lg;
  }
}

// ---------------- per-dst softmax (one wave, 8 sub-lanes per head) ----------------
__global__ void k_softmax(const float* __restrict__ logits, const int* __restrict__ order,
                          const int* __restrict__ offsets, float* __restrict__ alpha){
  int n = blockIdx.x, t = threadIdx.x;
  int head = t & 7, sub = t >> 3;         // lane = sub*8 + head
  int b = offsets[n], cnt = offsets[n+1]-b;
  float m = -1e30f;
  for (int i=sub;i<cnt;i+=8) m = fmaxf(m, logits[order[b+i]*HH + head]);
  m = fmaxf(m, __shfl_xor(m, 8));
  m = fmaxf(m, __shfl_xor(m, 16));
  m = fmaxf(m, __shfl_xor(m, 32));
  float z = 0;
  for (int i=sub;i<cnt;i+=8) z += expf(logits[order[b+i]*HH + head] - m);
  z += __shfl_xor(z, 8);
  z += __shfl_xor(z, 16);
  z += __shfl_xor(z, 32);
  float inv = 1.0f/(z + 1e-9f);
  for (int i=sub;i<cnt;i+=8){
    int e = order[b+i];
    alpha[e*HH+head] = expf(logits[e*HH+head]-m)*inv;
  }
}

// ---------------- heavy attention: one block per destination node ----------------
// All LDS tiles row-major [L][C]; A-operands are k4-unrolled b128 broadcasts
// (conflict-free), B-operands stride-16B rows (conflict-free).
// Next edge's wigner + h[src]+h[dst] prefetched into registers during compute.
__global__ __launch_bounds__(256,3)
void k_attn(const int* __restrict__ ei, const float* __restrict__ h,
            const float* __restrict__ wig_g, const float* __restrict__ rad,
            const float* __restrict__ alpha,
            const float* __restrict__ Wv, const float* __restrict__ Wo,
            const int* __restrict__ order, const int* __restrict__ offsets,
            float* __restrict__ x){
  __shared__ float wg  [32][28];  // wg[i][j] = wigner[e][i][j], pads zero
  __shared__ float wgT [32][28];  // wgT[i][j] = wigner[e][j][i], pads zero
  __shared__ float hsum[28][CC];  // rows 25-27 zero
  __shared__ float msg [32][CC];  // rows 25-31 computed-zero; reused as acc buffer
  __shared__ float vrow[28][CC];  // rows 25-27 zero

  int n = blockIdx.x;
  int b = offsets[n];
  int cnt = offsets[n+1]-b;
  if (cnt == 0) return;
  int t = threadIdx.x;
  int dt = t & 31, rt = t >> 5;
  int d0 = dt*4;          // col tile
  int i0 = rt*4;          // row tile

  // zero-init pads (uninitialized LDS may hold NaN patterns; 0*NaN = NaN)
  for (int i=t;i<32*28;i+=256){ ((float*)wg)[i]=0.0f; ((float*)wgT)[i]=0.0f; }
  for (int i=t;i<3*CC;i+=256){ hsum[25+(i>>7)][i&127]=0.0f; vrow[25+(i>>7)][i&127]=0.0f; }

  float acc[4][4];
  #pragma unroll
  for (int m=0;m<4;m++){ acc[m][0]=0; acc[m][1]=0; acc[m][2]=0; acc[m][3]=0; }

  // ---- stage first edge into registers ----
  float4 ph[4];
  float  pw[3];
  int e = order[b];
  {
    int s = ei[e], d = ei[EE+e];
    const float4* hs4 = (const float4*)(h + (size_t)s*LL*CC);
    const float4* hd4 = (const float4*)(h + (size_t)d*LL*CC);
    const float* we = wig_g + (size_t)e*625;
    #pragma unroll
    for (int k=0;k<4;k++){ int i2=t+256*k; if(i2<800){ float4 a=hs4[i2], bb=hd4[i2];
      ph[k]=make_float4(a.x+bb.x,a.y+bb.y,a.z+bb.z,a.w+bb.w);} }
    #pragma unroll
    for (int k=0;k<3;k++){ int i=t+256*k; if(i<625) pw[k]=we[i]; }
  }
  __syncthreads();   // pads zeroed
  // write first edge to LDS
  #pragma unroll
  for (int k=0;k<4;k++){ int i2=t+256*k; if(i2<800){ int r=i2>>5, c4=(i2&31)<<2;
    *(float4*)&hsum[r][c4]=ph[k]; } }
  #pragma unroll
  for (int k=0;k<3;k++){ int i=t+256*k; if(i<625){ int r=i/25, c=i-25*r;
    wg[r][c]=pw[k]; wgT[c][r]=pw[k]; } }
  __syncthreads();

  for (int idx=0; idx<cnt; ++idx){
    // current edge scalars
    float4 rad4 = *(const float4*)&rad[(size_t)e*CC + d0];
    float  al   = alpha[(size_t)e*HH + (d0>>4)];

    // prefetch next edge into registers (hidden under GEMMs)
    int e_next = (idx+1<cnt) ? order[b+idx+1] : e;
    {
      int s = ei[e_next], d = ei[EE+e_next];
      const float4* hs4 = (const float4*)(h + (size_t)s*LL*CC);
      const float4* hd4 = (const float4*)(h + (size_t)d*LL*CC);
      const float* we = wig_g + (size_t)e_next*625;
      #pragma unroll
      for (int k=0;k<4;k++){ int i2=t+256*k; if(i2<800){ float4 a=hs4[i2], bb=hd4[i2];
        ph[k]=make_float4(a.x+bb.x,a.y+bb.y,a.z+bb.z,a.w+bb.w);} }
      #pragma unroll
      for (int k=0;k<3;k++){ int i=t+256*k; if(i<625) pw[k]=we[i]; }
    }

    // GEMM1: msg[i][c] = sum_j wg[i][j]*hsum[j][c], then *rad
    {
      float cm[4][4];
      #pragma unroll
      for (int m=0;m<4;m++){ cm[m][0]=0; cm[m][1]=0; cm[m][2]=0; cm[m][3]=0; }
      for (int k4=0;k4<28;k4+=4){
        float4 a4[4], b4[4];
        #pragma unroll
        for (int m=0;m<4;m++) a4[m] = *(const float4*)&wg[i0+m][k4];
        #pragma unroll
        for (int kk=0;kk<4;kk++) b4[kk] = *(const float4*)&hsum[k4+kk][d0];
        #pragma unroll
        for (int kk=0;kk<4;kk++){
          float4 av = make_float4(getc(a4[0],kk),getc(a4[1],kk),getc(a4[2],kk),getc(a4[3],kk));
          fma16(cm, av, b4[kk]);
        }
      }
      #pragma unroll
      for (int m=0;m<4;m++)
        *(float4*)&msg[i0+m][d0] = make_float4(cm[m][0]*rad4.x, cm[m][1]*rad4.y,
                                               cm[m][2]*rad4.z, cm[m][3]*rad4.w);
    }
    __syncthreads();

    // GEMM2: v[i][d] = sum_c msg[i][c]*Wv[c][d]; *alpha; store vrow (masked)
    {
      float cm[4][4];
      #pragma unroll
      for (int m=0;m<4;m++){ cm[m][0]=0; cm[m][1]=0; cm[m][2]=0; cm[m][3]=0; }
      for (int k4=0;k4<CC;k4+=4){
        float4 a4[4], b4[4];
        #pragma unroll
        for (int m=0;m<4;m++) a4[m] = *(const float4*)&msg[i0+m][k4];
        #pragma unroll
        for (int kk=0;kk<4;kk++) b4[kk] = *(const float4*)&Wv[(k4+kk)*CC + d0];
        #pragma unroll
        for (int kk=0;kk<4;kk++){
          float4 av = make_float4(getc(a4[0],kk),getc(a4[1],kk),getc(a4[2],kk),getc(a4[3],kk));
          fma16(cm, av, b4[kk]);
        }
      }
      #pragma unroll
      for (int m=0;m<4;m++){
        int i = i0+m;
        if (i < LL)
          *(float4*)&vrow[i][d0] = make_float4(cm[m][0]*al, cm[m][1]*al, cm[m][2]*al, cm[m][3]*al);
      }
    }
    __syncthreads();

    // GEMM3: acc[i][c] += sum_j wgT[i][j]*vrow[j][c]
    {
      for (int k4=0;k4<28;k4+=4){
        float4 a4[4], b4[4];
        #pragma unroll
        for (int m=0;m<4;m++) a4[m] = *(const float4*)&wgT[i0+m][k4];
        #pragma unroll
        for (int kk=0;kk<4;kk++) b4[kk] = *(const float4*)&vrow[k4+kk][d0];
        #pragma unroll
        for (int kk=0;kk<4;kk++){
          float4 av = make_float4(getc(a4[0],kk),getc(a4[1],kk),getc(a4[2],kk),getc(a4[3],kk));
          fma16(acc, av, b4[kk]);
        }
      }
    }
    __syncthreads();

    // write next edge's wigner + hsum from registers to LDS
    #pragma unroll
    for (int k=0;k<4;k++){ int i2=t+256*k; if(i2<800){ int r=i2>>5, c4=(i2&31)<<2;
      *(float4*)&hsum[r][c4]=ph[k]; } }
    #pragma unroll
    for (int k=0;k<3;k++){ int i=t+256*k; if(i<625){ int r=i/25, c=i-25*r;
      wg[r][c]=pw[k]; wgT[c][r]=pw[k]; } }
    e = e_next;
    __syncthreads();
  }

  // dump acc rows into msg buffer (row-major, conflict-free)
  #pragma unroll
  for (int m=0;m<4;m++)
    *(float4*)&msg[i0+m][d0] = make_float4(acc[m][0], acc[m][1], acc[m][2], acc[m][3]);
  __syncthreads();

  // GEMM4: out[i][c'] = sum_d acc[i][d]*Wo[d][c']; residual into x
  {
    float co[4][4];
    #pragma unroll
    for (int m=0;m<4;m++){ co[m][0]=0; co[m][1]=0; co[m][2]=0; co[m][3]=0; }
    for (int k4=0;k4<CC;k4+=4){
      float4 a4[4], b4[4];
      #pragma unroll
      for (int m=0;m<4;m++) a4[m] = *(const float4*)&msg[i0+m][k4];
      #pragma unroll
      for (int kk=0;kk<4;kk++) b4[kk] = *(const float4*)&Wo[(k4+kk)*CC + d0];
      #pragma unroll
      for (int kk=0;kk<4;kk++){
        float4 av = make_float4(getc(a4[0],kk),getc(a4[1],kk),getc(a4[2],kk),getc(a4[3],kk));
        fma16(co, av, b4[kk]);
      }
    }
    #pragma unroll
    for (int m=0;m<4;m++){
      int i = i0+m;
      if (i < LL){
        float4 xv = *(float4*)&x[(size_t)n*LL*CC + i*CC + d0];
        xv.x += co[m][0]; xv.y += co[m][1]; xv.z += co[m][2]; xv.w += co[m][3];
        *(float4*)&x[(size_t)n*LL*CC + i*CC + d0] = xv;
      }
    }
  }
}

// ---------------- gated FFN (rmsnorm fused) ----------------
__global__ __launch_bounds__(256)
void k_ffn(float* __restrict__ x, const float* __restrict__ gamma,
           const float* __restrict__ Wf1, const float* __restrict__ Wg,
           const float* __restrict__ Wf2){
  __shared__ float xs[LL][CC];
  __shared__ float tT[CC][32];   // hT then hidT
  __shared__ float gs[FF];
  __shared__ float ps[2][CC];
  int t = threadIdx.x, n = blockIdx.x;
  float* xr = x + n*LL*CC;
  {
    float4* xs4 = (float4*)&xs[0][0];
    const float4* x4 = (const float4*)xr;
    for (int i=t;i<LL*CC/4;i+=256) xs4[i]=x4[i];
  }
  __syncthreads();
  int c = t&127, hf = t>>7;
  int r0 = hf?13:0, r1 = hf?LL:13;
  {
    float s=0;
    for (int r=r0;r<r1;r++){ float v=xs[r][c]; s += v*v; }
    ps[hf][c]=s;
  }
  __syncthreads();
  float rn = 1.0f/sqrtf((ps[0][c]+ps[1][c])*(1.0f/(float)LL) + 1e-6f);
  float gm = gamma[c]*rn;
  for (int r=r0;r<r1;r++) tT[c][r] = xs[r][c]*gm;
  for (int r=LL + (hf?13:0) - (hf?13:0); r<LL;r++) {}   // no-op
  if (hf==0) { for (int r=LL;r<32;r++) tT[c][r] = 0.0f; }  // zero pad rows 25-31 of hT cols
  __syncthreads();
  // gate from h[0,:]
  if (t < FF){
    float gv=0;
    for (int k=0;k<CC;k++) gv += tT[k][0]*Wg[k*FF+t];
    gs[t] = silu_f(gv);
  }
  int dt=t&31, rt=t>>5, d0=dt*4, i0=rt*4;
  float cm[4][4];
  #pragma unroll
  for (int m=0;m<4;m++){ cm[m][0]=0; cm[m][1]=0; cm[m][2]=0; cm[m][3]=0; }
  #pragma unroll 4
  for (int k=0;k<CC;k++){
    float4 av = *(const float4*)&tT[k][i0];
    float4 bv = *(const float4*)&Wf1[k*FF+d0];
    fma16(cm, av, bv);
  }
  __syncthreads();   // all GEMM1 reads of tT done; gs visible
  #pragma unroll
  for (int j=0;j<4;j++){
    float gj = gs[d0+j];
    *(float4*)&tT[d0+j][i0] = make_float4(cm[0][j]*gj, cm[1][j]*gj, cm[2][j]*gj, cm[3][j]*gj);
  }
  __syncthreads();
  float co[4][4];
  #pragma unroll
  for (int m=0;m<4;m++){ co[m][0]=0; co[m][1]=0; co[m][2]=0; co[m][3]=0; }
  #pragma unroll 4
  for (int k=0;k<FF;k++){
    float4 av = *(const float4*)&tT[k][i0];
    float4 bv = *(const float4*)&Wf2[k*CC+d0];
    fma16(co, av, bv);
  }
  #pragma unroll
  for (int m=0;m<4;m++){
    int i=i0+m;
    if (i<LL){
      float4 xv = *(float4*)&xs[i][d0];
      xv.x+=co[m][0]; xv.y+=co[m][1]; xv.z+=co[m][2]; xv.w+=co[m][3];
      *(float4*)&xr[i*CC+d0] = xv;
    }
  }
}

extern "C" void kernel_launch(void* const* d_in, const int* in_sizes, int n_in,
                              void* d_out, int out_size, void* d_ws, size_t ws_size,
                              hipStream_t stream){
  const int*   zn       = (const int*)  d_in[0];
  const float* pos      = (const float*)d_in[1];
  const int*   ei       = (const int*)  d_in[2];
  const float* wig      = (const float*)d_in[3];
  const float* atom_emb = (const float*)d_in[4];
  const float* src_emb  = (const float*)d_in[5];
  const float* dst_emb  = (const float*)d_in[6];
  const float* W_e1     = (const float*)d_in[7];
  const float* W_e2     = (const float*)d_in[8];
  const float* g_attn   = (const float*)d_in[9];
  const float* g_ffn    = (const float*)d_in[10];
  const float* W_rad    = (const float*)d_in[11];
  const float* W_a1     = (const float*)d_in[12];
  const float* w_a2     = (const float*)d_in[13];
  const float* W_val    = (const float*)d_in[14];
  const float* W_out    = (const float*)d_in[15];
  const float* W_f1     = (const float*)d_in[16];
  const float* W_g      = (const float*)d_in[17];
  const float* W_f2     = (const float*)d_in[18];
  float* x = (float*)d_out;

  char* w = (char*)d_ws;
  float* h      = (float*)w;  w += (size_t)NN*LL*CC*4;
  float* rad0   = (float*)w;  w += (size_t)EE*CC*4;
  float* rad1   = (float*)w;  w += (size_t)EE*CC*4;
  float* logits = (float*)w;  w += (size_t)EE*HH*4;
  float* alpha  = (float*)w;  w += (size_t)EE*HH*4;
  int* order    = (int*)w;    w += (size_t)EE*4;
  int* counts   = (int*)w;    w += (size_t)NN*4;
  int* offsets  = (int*)w;    w += (size_t)(NN+4)*4;
  int* cursor   = (int*)w;    w += (size_t)NN*4;

  hipMemsetAsync(counts, 0, NN*4, stream);
  hipMemsetAsync(cursor, 0, NN*4, stream);
  k_hist   <<<(EE+255)/256,256,0,stream>>>(ei, counts);
  k_scan   <<<1,256,0,stream>>>(counts, offsets);
  k_scatter<<<(EE+255)/256,256,0,stream>>>(ei, offsets, cursor, order);
  k_edge   <<<EE/8,256,0,stream>>>(ei, zn, pos, src_emb, dst_emb, W_e1, W_e2, W_rad, rad0, rad1);
  k_init_x <<<(NN*LL*CC)/256,256,0,stream>>>(zn, atom_emb, x);

  for (int l=0;l<2;l++){
    const float* radl = l? rad1:rad0;
    k_rms    <<<NN,256,0,stream>>>(x, g_attn + l*CC, h);
    k_logits <<<EE/8,256,0,stream>>>(ei, h, radl, wig, W_a1 + l*CC*HH*AA, w_a2 + l*HH*AA, logits);
    k_softmax<<<NN,64,0,stream>>>(logits, order, offsets, alpha);
    k_attn   <<<NN,256,0,stream>>>(ei, h, wig, radl, alpha, W_val + l*CC*HH*VV,
                                   W_out + l*HH*VV*CC, order, offsets, x);
    k_ffn    <<<NN,256,0,stream>>>(x, g_ffn + l*CC, W_f1 + l*CC*FF, W_g + l*CC*FF, W_f2 + l*FF*CC);
  }
}

// Round 3
// 5059.137 us; speedup vs baseline: 11.6455x; 11.6455x over previous
//
#include <hip/hip_runtime.h>
#include <math.h>

#define NN 2500
#define EE 50000
#define CC 128
#define LL 25
#define HH 8
#define AA 64
#define VV 16
#define FF 128
#define NBASIS 600
#define EFD (NBASIS + 2*CC)   // 856

__device__ __forceinline__ float silu_f(float x){ return x / (1.0f + expf(-x)); }

__device__ __forceinline__ void fma16(float (&cm)[4][4], const float4& av, const float4& bv){
  cm[0][0]+=av.x*bv.x; cm[0][1]+=av.x*bv.y; cm[0][2]+=av.x*bv.z; cm[0][3]+=av.x*bv.w;
  cm[1][0]+=av.y*bv.x; cm[1][1]+=av.y*bv.y; cm[1][2]+=av.y*bv.z; cm[1][3]+=av.y*bv.w;
  cm[2][0]+=av.z*bv.x; cm[2][1]+=av.z*bv.y; cm[2][2]+=av.z*bv.z; cm[2][3]+=av.z*bv.w;
  cm[3][0]+=av.w*bv.x; cm[3][1]+=av.w*bv.y; cm[3][2]+=av.w*bv.z; cm[3][3]+=av.w*bv.w;
}

// one k4-step of a 4x4-tile GEMM with row-major A segments; all named locals,
// static member access only (spill-proof per rule #20)
__device__ __forceinline__ void gemm_step4(float (&cm)[4][4],
    const float4& A0, const float4& A1, const float4& A2, const float4& A3,
    const float4& B0, const float4& B1, const float4& B2, const float4& B3){
  fma16(cm, make_float4(A0.x,A1.x,A2.x,A3.x), B0);
  fma16(cm, make_float4(A0.y,A1.y,A2.y,A3.y), B1);
  fma16(cm, make_float4(A0.z,A1.z,A2.z,A3.z), B2);
  fma16(cm, make_float4(A0.w,A1.w,A2.w,A3.w), B3);
}

// ---------------- edge sort by dst (counting sort) ----------------
__global__ void k_hist(const int* __restrict__ ei, int* __restrict__ counts){
  int e = blockIdx.x*256 + threadIdx.x;
  if (e < EE) atomicAdd(&counts[ei[EE+e]], 1);
}

__global__ void k_scan(const int* __restrict__ counts, int* __restrict__ offsets){
  __shared__ int part[256];
  __shared__ int partx[257];
  int t = threadIdx.x;
  const int chunk = (NN + 255)/256;   // 10
  int base = t*chunk;
  int s = 0;
  for (int i=0;i<chunk;i++){ int idx=base+i; if (idx<NN) s += counts[idx]; }
  part[t] = s;
  __syncthreads();
  if (t==0){ int acc=0; for (int i=0;i<256;i++){ partx[i]=acc; acc+=part[i]; } partx[256]=acc; }
  __syncthreads();
  int acc = partx[t];
  for (int i=0;i<chunk;i++){ int idx=base+i; if (idx<NN){ offsets[idx]=acc; acc+=counts[idx]; } }
  if (t==0) offsets[NN] = partx[256];
}

__global__ void k_scatter(const int* __restrict__ ei, const int* __restrict__ offsets,
                          int* __restrict__ cursor, int* __restrict__ order){
  int e = blockIdx.x*256 + threadIdx.x;
  if (e < EE){
    int d = ei[EE+e];
    int p = atomicAdd(&cursor[d], 1);
    order[offsets[d]+p] = e;
  }
}

// ---------------- init x: only l=0 row populated ----------------
__global__ void k_init_x(const int* __restrict__ zn, const float* __restrict__ atom_emb,
                         float* __restrict__ x){
  int idx = blockIdx.x*256 + threadIdx.x;
  int n = idx / (LL*CC);
  int r = idx - n*(LL*CC);
  float v = 0.0f;
  if (r < CC) v = atom_emb[zn[n]*CC + r];
  x[idx] = v;
}

// ---------------- edge scalar features -> rad0, rad1 ----------------
__global__ __launch_bounds__(256)
void k_edge(const int* __restrict__ ei, const int* __restrict__ zn,
            const float* __restrict__ pos,
            const float* __restrict__ src_emb, const float* __restrict__ dst_emb,
            const float* __restrict__ W_e1, const float* __restrict__ W_e2,
            const float* __restrict__ W_rad,
            float* __restrict__ rad0, float* __restrict__ rad1){
  __shared__ float feat[8][EFD];
  __shared__ float efl[8][CC];
  __shared__ float dist[8];
  int t = threadIdx.x;
  int e0 = blockIdx.x*8;
  if (t < 8){
    int e = e0+t;
    int s = ei[e], d = ei[EE+e];
    float dx = pos[s*3]-pos[d*3], dy = pos[s*3+1]-pos[d*3+1], dz = pos[s*3+2]-pos[d*3+2];
    dist[t] = sqrtf(dx*dx+dy*dy+dz*dz);
  }
  __syncthreads();
  const float step = 12.0f/599.0f;
  const float coeff = -0.5f/((2.0f*step)*(2.0f*step));
  for (int eidx=0; eidx<8; ++eidx){
    int e = e0+eidx;
    int zs = zn[ei[e]], zd = zn[ei[EE+e]];
    float de = dist[eidx];
    for (int k=t;k<EFD;k+=256){
      float v;
      if (k < NBASIS){ float u = de - k*step; v = expf(coeff*u*u); }
      else if (k < NBASIS+CC) v = src_emb[zs*CC + (k-NBASIS)];
      else v = dst_emb[zd*CC + (k-NBASIS-CC)];
      feat[eidx][k] = v;
    }
  }
  __syncthreads();
  int eidx = t>>5;
  int c0 = (t&31)*4;
  float a0=0,a1=0,a2=0,a3=0;
  for (int k=0;k<EFD;k++){
    float f = feat[eidx][k];
    const float4 w = *(const float4*)&W_e1[k*CC + c0];
    a0 += f*w.x; a1 += f*w.y; a2 += f*w.z; a3 += f*w.w;
  }
  efl[eidx][c0]=silu_f(a0); efl[eidx][c0+1]=silu_f(a1); efl[eidx][c0+2]=silu_f(a2); efl[eidx][c0+3]=silu_f(a3);
  __syncthreads();
  a0=a1=a2=a3=0;
  for (int k=0;k<CC;k++){
    float f = efl[eidx][k];
    const float4 w = *(const float4*)&W_e2[k*CC+c0];
    a0 += f*w.x; a1 += f*w.y; a2 += f*w.z; a3 += f*w.w;
  }
  __syncthreads();
  efl[eidx][c0]=silu_f(a0); efl[eidx][c0+1]=silu_f(a1); efl[eidx][c0+2]=silu_f(a2); efl[eidx][c0+3]=silu_f(a3);
  __syncthreads();
  #pragma unroll
  for (int l=0;l<2;l++){
    const float* Wr = W_rad + l*CC*CC;
    float r0=0,r1=0,r2=0,r3=0;
    for (int k=0;k<CC;k++){
      float f = efl[eidx][k];
      const float4 w = *(const float4*)&Wr[k*CC+c0];
      r0+=f*w.x; r1+=f*w.y; r2+=f*w.z; r3+=f*w.w;
    }
    float* out = l ? rad1 : rad0;
    *(float4*)&out[(e0+eidx)*CC + c0] = make_float4(r0,r1,r2,r3);
  }
}

// ---------------- equivariant RMS norm -> h ----------------
__global__ __launch_bounds__(256)
void k_rms(const float* __restrict__ x, const float* __restrict__ gamma, float* __restrict__ h){
  __shared__ float xs[LL][CC];
  __shared__ float ps[2][CC];
  int t = threadIdx.x, n = blockIdx.x;
  const float* xr = x + n*LL*CC;
  {
    float4* xs4 = (float4*)&xs[0][0];
    const float4* x4 = (const float4*)xr;
    for (int i=t;i<LL*CC/4;i+=256) xs4[i]=x4[i];
  }
  __syncthreads();
  int c = t&127, hf = t>>7;
  int r0 = hf?13:0, r1 = hf?LL:13;
  float s=0;
  for (int r=r0;r<r1;r++){ float v = xs[r][c]; s += v*v; }
  ps[hf][c]=s;
  __syncthreads();
  float rn = 1.0f/sqrtf((ps[0][c]+ps[1][c])*(1.0f/(float)LL) + 1e-6f);
  float g = gamma[c]*rn;
  float* hr = h + n*LL*CC;
  for (int r=r0;r<r1;r++) hr[r*CC+c] = xs[r][c]*g;
}

// ---------------- attention logits ----------------
__global__ __launch_bounds__(256)
void k_logits(const int* __restrict__ ei, const float* __restrict__ h,
              const float* __restrict__ rad, const float* __restrict__ wig,
              const float* __restrict__ Wa1, const float* __restrict__ wa2,
              float* __restrict__ logits){
  __shared__ float w0[8][LL];
  __shared__ float m0[8][CC];
  __shared__ float aS[8][HH*AA];
  int t = threadIdx.x;
  int e0 = blockIdx.x*8;
  for (int i=t;i<8*LL;i+=256){
    int eidx = i/LL, j = i - eidx*LL;
    w0[eidx][j] = wig[(e0+eidx)*625 + j];
  }
  __syncthreads();
  {
    int c = t&127, eg = t>>7;
    for (int j=0;j<4;j++){
      int e = e0 + eg*4 + j;
      int s = ei[e], d = ei[EE+e];
      const float* hs = h + s*LL*CC + c;
      const float* hd = h + d*LL*CC + c;
      float acc = 0;
      #pragma unroll
      for (int r=0;r<LL;r++) acc += w0[eg*4+j][r]*(hs[r*CC]+hd[r*CC]);
      m0[eg*4+j][c] = acc*rad[e*CC+c];
    }
  }
  __syncthreads();
  float accA[16];
  #pragma unroll
  for (int i=0;i<16;i++) accA[i]=0;
  for (int k=0;k<CC;k++){
    float wv0 = Wa1[k*512 + t];
    float wv1 = Wa1[k*512 + 256 + t];
    #pragma unroll
    for (int e=0;e<8;e++){
      float mv = m0[e][k];
      accA[e*2]   += mv*wv0;
      accA[e*2+1] += mv*wv1;
    }
  }
  #pragma unroll
  for (int e=0;e<8;e++){ aS[e][t]=silu_f(accA[e*2]); aS[e][256+t]=silu_f(accA[e*2+1]); }
  __syncthreads();
  if (t < 64){
    int eidx = t>>3, hh2 = t&7;
    float lg = 0;
    #pragma unroll
    for (int a=0;a<AA;a++) lg += aS[eidx][hh2*AA+a]*wa2[hh2*AA+a];
    logits[(e0+eidx)*HH + hh2] = lg;
  }
}

// ---------------- per-dst softmax (one wave, 8 sub-lanes per head) ----------------
__global__ void k_softmax(const float* __restrict__ logits, const int* __restrict__ order,
                          const int* __restrict__ offsets, float* __restrict__ alpha){
  int n = blockIdx.x, t = threadIdx.x;
  int head = t & 7, sub = t >> 3;
  int b = offsets[n], cnt = offsets[n+1]-b;
  float m = -1e30f;
  for (int i=sub;i<cnt;i+=8) m = fmaxf(m, logits[order[b+i]*HH + head]);
  m = fmaxf(m, __shfl_xor(m, 8));
  m = fmaxf(m, __shfl_xor(m, 16));
  m = fmaxf(m, __shfl_xor(m, 32));
  float z = 0;
  for (int i=sub;i<cnt;i+=8) z += expf(logits[order[b+i]*HH + head] - m);
  z += __shfl_xor(z, 8);
  z += __shfl_xor(z, 16);
  z += __shfl_xor(z, 32);
  float inv = 1.0f/(z + 1e-9f);
  for (int i=sub;i<cnt;i+=8){
    int e = order[b+i];
    alpha[e*HH+head] = expf(logits[e*HH+head]-m)*inv;
  }
}

// ---------------- heavy attention: one block per destination node ----------------
// LDS layouts (all conflict-free for their access patterns):
//   wigA[k][i] = wig[i][k]  (GEMM1 A: float4 broadcast read per k)
//   wigB[k][i] = wig[k][i]  (GEMM3 A)
//   hsum/msg/vrow row-major [l][c]: float4 stores along c (lane-consecutive)
// Next edge's wigner + h staged in NAMED registers (no arrays -> no scratch),
// issued after GEMM1's barrier, retired after GEMM2/GEMM3.
__global__ __launch_bounds__(256)
void k_attn(const int* __restrict__ ei, const float* __restrict__ h,
            const float* __restrict__ wig_g, const float* __restrict__ rad,
            const float* __restrict__ alpha,
            const float* __restrict__ Wv, const float* __restrict__ Wo,
            const int* __restrict__ order, const int* __restrict__ offsets,
            float* __restrict__ x){
  __shared__ float wigA[28][32];
  __shared__ float wigB[28][32];
  __shared__ float hsum[28][CC];
  __shared__ float msg [32][CC];   // reused for acc before GEMM4
  __shared__ float vrow[28][CC];

  int n = blockIdx.x;
  int b = offsets[n];
  int cnt = offsets[n+1]-b;
  if (cnt == 0) return;
  int t = threadIdx.x;
  int dt = t & 31, rt = t >> 5;
  int d0 = dt*4;
  int i0 = rt*4;

  // zero everything once: pads persist (edge writes only touch [0..24] ranges)
  for (int i=t;i<28*32;i+=256){ ((float*)wigA)[i]=0.0f; ((float*)wigB)[i]=0.0f; }
  for (int i=t;i<3*CC;i+=256){ hsum[25+(i>>7)][i&127]=0.0f; vrow[25+(i>>7)][i&127]=0.0f; }

  float acc[4][4];
  #pragma unroll
  for (int m=0;m<4;m++){ acc[m][0]=0; acc[m][1]=0; acc[m][2]=0; acc[m][3]=0; }

  // ---- prologue: stage first edge ----
  int e = order[b];
  float4 ph0, ph1, ph2, ph3;
  float  pw0, pw1, pw2;
  float4 rad4; float al;
  {
    int s = ei[e], d = ei[EE+e];
    const float4* hs4 = (const float4*)(h + (size_t)s*LL*CC);
    const float4* hd4 = (const float4*)(h + (size_t)d*LL*CC);
    const float* we = wig_g + (size_t)e*625;
    float4 a, bb;
    a=hs4[t];     bb=hd4[t];     ph0=make_float4(a.x+bb.x,a.y+bb.y,a.z+bb.z,a.w+bb.w);
    a=hs4[t+256]; bb=hd4[t+256]; ph1=make_float4(a.x+bb.x,a.y+bb.y,a.z+bb.z,a.w+bb.w);
    a=hs4[t+512]; bb=hd4[t+512]; ph2=make_float4(a.x+bb.x,a.y+bb.y,a.z+bb.z,a.w+bb.w);
    if (t < 32){ a=hs4[t+768]; bb=hd4[t+768]; ph3=make_float4(a.x+bb.x,a.y+bb.y,a.z+bb.z,a.w+bb.w); }
    pw0 = we[t];
    pw1 = we[t+256];
    if (t < 113) pw2 = we[t+512];
    rad4 = *(const float4*)&rad[(size_t)e*CC + d0];
    al   = alpha[(size_t)e*HH + (d0>>4)];
  }
  __syncthreads();   // zero-init done
  {
    int i2;
    i2=t;     { *(float4*)&hsum[i2>>5][(i2&31)*4]=ph0; }
    i2=t+256; { *(float4*)&hsum[i2>>5][(i2&31)*4]=ph1; }
    i2=t+512; { *(float4*)&hsum[i2>>5][(i2&31)*4]=ph2; }
    if (t<32){ i2=t+768; *(float4*)&hsum[i2>>5][(i2&31)*4]=ph3; }
    int i; int r; int c;
    i=t;             r=i/25; c=i-25*r; wigA[c][r]=pw0; wigB[r][c]=pw0;
    i=t+256;         r=i/25; c=i-25*r; wigA[c][r]=pw1; wigB[r][c]=pw1;
    if (t<113){ i=t+512; r=i/25; c=i-25*r; wigA[c][r]=pw2; wigB[r][c]=pw2; }
  }
  __syncthreads();

  for (int idx=0; idx<cnt; ++idx){
    float4 radc = rad4; float alc = al;
    int e_next = (idx+1<cnt) ? order[b+idx+1] : e;

    // GEMM1: msg[i][c] = (sum_k wig[i][k]*hsum[k][c]) * rad[c]
    {
      float cm[4][4];
      #pragma unroll
      for (int m=0;m<4;m++){ cm[m][0]=0; cm[m][1]=0; cm[m][2]=0; cm[m][3]=0; }
      for (int k=0;k<28;k++){
        float4 av = *(const float4*)&wigA[k][i0];
        float4 bv = *(const float4*)&hsum[k][d0];
        fma16(cm, av, bv);
      }
      #pragma unroll
      for (int m=0;m<4;m++)
        *(float4*)&msg[i0+m][d0] = make_float4(cm[m][0]*radc.x, cm[m][1]*radc.y,
                                               cm[m][2]*radc.z, cm[m][3]*radc.w);
    }
    __syncthreads();   // barrier1: msg ready, hsum dead

    // issue next edge's loads (named regs; retired below, hidden under GEMM2)
    {
      int s = ei[e_next], d = ei[EE+e_next];
      const float4* hs4 = (const float4*)(h + (size_t)s*LL*CC);
      const float4* hd4 = (const float4*)(h + (size_t)d*LL*CC);
      const float* we = wig_g + (size_t)e_next*625;
      float4 a, bb;
      a=hs4[t];     bb=hd4[t];     ph0=make_float4(a.x+bb.x,a.y+bb.y,a.z+bb.z,a.w+bb.w);
      a=hs4[t+256]; bb=hd4[t+256]; ph1=make_float4(a.x+bb.x,a.y+bb.y,a.z+bb.z,a.w+bb.w);
      a=hs4[t+512]; bb=hd4[t+512]; ph2=make_float4(a.x+bb.x,a.y+bb.y,a.z+bb.z,a.w+bb.w);
      if (t < 32){ a=hs4[t+768]; bb=hd4[t+768]; ph3=make_float4(a.x+bb.x,a.y+bb.y,a.z+bb.z,a.w+bb.w); }
      pw0 = we[t];
      pw1 = we[t+256];
      if (t < 113) pw2 = we[t+512];
      rad4 = *(const float4*)&rad[(size_t)e_next*CC + d0];
      al   = alpha[(size_t)e_next*HH + (d0>>4)];
    }

    // GEMM2: v[i][d] = sum_c msg[i][c]*Wv[c][d]; *alpha; store vrow
    {
      float cm[4][4];
      #pragma unroll
      for (int m=0;m<4;m++){ cm[m][0]=0; cm[m][1]=0; cm[m][2]=0; cm[m][3]=0; }
      for (int k4=0;k4<CC;k4+=4){
        float4 A0 = *(const float4*)&msg[i0+0][k4];
        float4 A1 = *(const float4*)&msg[i0+1][k4];
        float4 A2 = *(const float4*)&msg[i0+2][k4];
        float4 A3 = *(const float4*)&msg[i0+3][k4];
        float4 B0 = *(const float4*)&Wv[(k4+0)*CC + d0];
        float4 B1 = *(const float4*)&Wv[(k4+1)*CC + d0];
        float4 B2 = *(const float4*)&Wv[(k4+2)*CC + d0];
        float4 B3 = *(const float4*)&Wv[(k4+3)*CC + d0];
        gemm_step4(cm, A0,A1,A2,A3, B0,B1,B2,B3);
      }
      #pragma unroll
      for (int m=0;m<4;m++){
        int i = i0+m;
        if (i < LL)
          *(float4*)&vrow[i][d0] = make_float4(cm[m][0]*alc, cm[m][1]*alc, cm[m][2]*alc, cm[m][3]*alc);
      }
    }
    // retire h prefetch into hsum (safe: all waves past barrier1; GEMM2 doesn't read hsum)
    {
      int i2;
      i2=t;     *(float4*)&hsum[i2>>5][(i2&31)*4]=ph0;
      i2=t+256; *(float4*)&hsum[i2>>5][(i2&31)*4]=ph1;
      i2=t+512; *(float4*)&hsum[i2>>5][(i2&31)*4]=ph2;
      if (t<32){ i2=t+768; *(float4*)&hsum[i2>>5][(i2&31)*4]=ph3; }
    }
    __syncthreads();   // barrier2: vrow ready

    // GEMM3: acc[i][c] += sum_k wig[k][i]*vrow[k][c]
    for (int k=0;k<28;k++){
      float4 av = *(const float4*)&wigB[k][i0];
      float4 bv = *(const float4*)&vrow[k][d0];
      fma16(acc, av, bv);
    }
    __syncthreads();   // barrier3: wig arrays dead for all waves

    // retire wigner prefetch
    {
      int i, r, c;
      i=t;             r=i/25; c=i-25*r; wigA[c][r]=pw0; wigB[r][c]=pw0;
      i=t+256;         r=i/25; c=i-25*r; wigA[c][r]=pw1; wigB[r][c]=pw1;
      if (t<113){ i=t+512; r=i/25; c=i-25*r; wigA[c][r]=pw2; wigB[r][c]=pw2; }
    }
    e = e_next;
    __syncthreads();   // barrier4: next edge staged
  }

  // dump acc into msg (row-major, conflict-free)
  #pragma unroll
  for (int m=0;m<4;m++)
    *(float4*)&msg[i0+m][d0] = make_float4(acc[m][0], acc[m][1], acc[m][2], acc[m][3]);
  __syncthreads();

  // GEMM4: out[i][c'] = sum_d acc[i][d]*Wo[d][c']; residual into x
  {
    float co[4][4];
    #pragma unroll
    for (int m=0;m<4;m++){ co[m][0]=0; co[m][1]=0; co[m][2]=0; co[m][3]=0; }
    for (int k4=0;k4<CC;k4+=4){
      float4 A0 = *(const float4*)&msg[i0+0][k4];
      float4 A1 = *(const float4*)&msg[i0+1][k4];
      float4 A2 = *(const float4*)&msg[i0+2][k4];
      float4 A3 = *(const float4*)&msg[i0+3][k4];
      float4 B0 = *(const float4*)&Wo[(k4+0)*CC + d0];
      float4 B1 = *(const float4*)&Wo[(k4+1)*CC + d0];
      float4 B2 = *(const float4*)&Wo[(k4+2)*CC + d0];
      float4 B3 = *(const float4*)&Wo[(k4+3)*CC + d0];
      gemm_step4(co, A0,A1,A2,A3, B0,B1,B2,B3);
    }
    #pragma unroll
    for (int m=0;m<4;m++){
      int i = i0+m;
      if (i < LL){
        float4 xv = *(float4*)&x[(size_t)n*LL*CC + i*CC + d0];
        xv.x += co[m][0]; xv.y += co[m][1]; xv.z += co[m][2]; xv.w += co[m][3];
        *(float4*)&x[(size_t)n*LL*CC + i*CC + d0] = xv;
      }
    }
  }
}

// ---------------- gated FFN (rmsnorm fused) ----------------
__global__ __launch_bounds__(256)
void k_ffn(float* __restrict__ x, const float* __restrict__ gamma,
           const float* __restrict__ Wf1, const float* __restrict__ Wg,
           const float* __restrict__ Wf2){
  __shared__ float xs[LL][CC];
  __shared__ float tT[CC][32];   // hT then hidT
  __shared__ float gs[FF];
  __shared__ float ps[2][CC];
  int t = threadIdx.x, n = blockIdx.x;
  float* xr = x + n*LL*CC;
  {
    float4* xs4 = (float4*)&xs[0][0];
    const float4* x4 = (const float4*)xr;
    for (int i=t;i<LL*CC/4;i+=256) xs4[i]=x4[i];
  }
  __syncthreads();
  int c = t&127, hf = t>>7;
  int r0 = hf?13:0, r1 = hf?LL:13;
  {
    float s=0;
    for (int r=r0;r<r1;r++){ float v=xs[r][c]; s += v*v; }
    ps[hf][c]=s;
  }
  __syncthreads();
  float rn = 1.0f/sqrtf((ps[0][c]+ps[1][c])*(1.0f/(float)LL) + 1e-6f);
  float gm = gamma[c]*rn;
  for (int r=r0;r<r1;r++) tT[c][r] = xs[r][c]*gm;
  if (hf==0){ for (int r=LL;r<32;r++) tT[c][r] = 0.0f; }
  __syncthreads();
  if (t < FF){
    float gv=0;
    for (int k=0;k<CC;k++) gv += tT[k][0]*Wg[k*FF+t];
    gs[t] = silu_f(gv);
  }
  int dt=t&31, rt=t>>5, d0=dt*4, i0=rt*4;
  float cm[4][4];
  #pragma unroll
  for (int m=0;m<4;m++){ cm[m][0]=0; cm[m][1]=0; cm[m][2]=0; cm[m][3]=0; }
  #pragma unroll 4
  for (int k=0;k<CC;k++){
    float4 av = *(const float4*)&tT[k][i0];
    float4 bv = *(const float4*)&Wf1[k*FF+d0];
    fma16(cm, av, bv);
  }
  __syncthreads();
  #pragma unroll
  for (int j=0;j<4;j++){
    float gj = gs[d0+j];
    *(float4*)&tT[d0+j][i0] = make_float4(cm[0][j]*gj, cm[1][j]*gj, cm[2][j]*gj, cm[3][j]*gj);
  }
  __syncthreads();
  float co[4][4];
  #pragma unroll
  for (int m=0;m<4;m++){ co[m][0]=0; co[m][1]=0; co[m][2]=0; co[m][3]=0; }
  #pragma unroll 4
  for (int k=0;k<FF;k++){
    float4 av = *(const float4*)&tT[k][i0];
    float4 bv = *(const float4*)&Wf2[k*CC+d0];
    fma16(co, av, bv);
  }
  #pragma unroll
  for (int m=0;m<4;m++){
    int i=i0+m;
    if (i<LL){
      float4 xv = *(float4*)&xs[i][d0];
      xv.x+=co[m][0]; xv.y+=co[m][1]; xv.z+=co[m][2]; xv.w+=co[m][3];
      *(float4*)&xr[i*CC+d0] = xv;
    }
  }
}

extern "C" void kernel_launch(void* const* d_in, const int* in_sizes, int n_in,
                              void* d_out, int out_size, void* d_ws, size_t ws_size,
                              hipStream_t stream){
  const int*   zn       = (const int*)  d_in[0];
  const float* pos      = (const float*)d_in[1];
  const int*   ei       = (const int*)  d_in[2];
  const float* wig      = (const float*)d_in[3];
  const float* atom_emb = (const float*)d_in[4];
  const float* src_emb  = (const float*)d_in[5];
  const float* dst_emb  = (const float*)d_in[6];
  const float* W_e1     = (const float*)d_in[7];
  const float* W_e2     = (const float*)d_in[8];
  const float* g_attn   = (const float*)d_in[9];
  const float* g_ffn    = (const float*)d_in[10];
  const float* W_rad    = (const float*)d_in[11];
  const float* W_a1     = (const float*)d_in[12];
  const float* w_a2     = (const float*)d_in[13];
  const float* W_val    = (const float*)d_in[14];
  const float* W_out    = (const float*)d_in[15];
  const float* W_f1     = (const float*)d_in[16];
  const float* W_g      = (const float*)d_in[17];
  const float* W_f2     = (const float*)d_in[18];
  float* x = (float*)d_out;

  char* w = (char*)d_ws;
  float* h      = (float*)w;  w += (size_t)NN*LL*CC*4;
  float* rad0   = (float*)w;  w += (size_t)EE*CC*4;
  float* rad1   = (float*)w;  w += (size_t)EE*CC*4;
  float* logits = (float*)w;  w += (size_t)EE*HH*4;
  float* alpha  = (float*)w;  w += (size_t)EE*HH*4;
  int* order    = (int*)w;    w += (size_t)EE*4;
  int* counts   = (int*)w;    w += (size_t)NN*4;
  int* offsets  = (int*)w;    w += (size_t)(NN+4)*4;
  int* cursor   = (int*)w;    w += (size_t)NN*4;

  hipMemsetAsync(counts, 0, NN*4, stream);
  hipMemsetAsync(cursor, 0, NN*4, stream);
  k_hist   <<<(EE+255)/256,256,0,stream>>>(ei, counts);
  k_scan   <<<1,256,0,stream>>>(counts, offsets);
  k_scatter<<<(EE+255)/256,256,0,stream>>>(ei, offsets, cursor, order);
  k_edge   <<<EE/8,256,0,stream>>>(ei, zn, pos, src_emb, dst_emb, W_e1, W_e2, W_rad, rad0, rad1);
  k_init_x <<<(NN*LL*CC)/256,256,0,stream>>>(zn, atom_emb, x);

  for (int l=0;l<2;l++){
    const float* radl = l? rad1:rad0;
    k_rms    <<<NN,256,0,stream>>>(x, g_attn + l*CC, h);
    k_logits <<<EE/8,256,0,stream>>>(ei, h, radl, wig, W_a1 + l*CC*HH*AA, w_a2 + l*HH*AA, logits);
    k_softmax<<<NN,64,0,stream>>>(logits, order, offsets, alpha);
    k_attn   <<<NN,256,0,stream>>>(ei, h, wig, radl, alpha, W_val + l*CC*HH*VV,
                                   W_out + l*HH*VV*CC, order, offsets, x);
    k_ffn    <<<NN,256,0,stream>>>(x, g_ffn + l*CC, W_f1 + l*CC*FF, W_g + l*CC*FF, W_f2 + l*FF*CC);
  }
}

// Round 4
// 3028.519 us; speedup vs baseline: 19.4538x; 1.6705x over previous
//
#include <hip/hip_runtime.h>
#include <math.h>

#define NN 2500
#define EE 50000
#define CC 128
#define LL 25
#define HH 8
#define AA 64
#define VV 16
#define FF 128
#define NBASIS 600
#define EFD (NBASIS + 2*CC)   // 856

__device__ __forceinline__ float silu_f(float x){ return x / (1.0f + expf(-x)); }

__device__ __forceinline__ void fma16(float (&cm)[4][4], const float4& av, const float4& bv){
  cm[0][0]+=av.x*bv.x; cm[0][1]+=av.x*bv.y; cm[0][2]+=av.x*bv.z; cm[0][3]+=av.x*bv.w;
  cm[1][0]+=av.y*bv.x; cm[1][1]+=av.y*bv.y; cm[1][2]+=av.y*bv.z; cm[1][3]+=av.y*bv.w;
  cm[2][0]+=av.z*bv.x; cm[2][1]+=av.z*bv.y; cm[2][2]+=av.z*bv.z; cm[2][3]+=av.z*bv.w;
  cm[3][0]+=av.w*bv.x; cm[3][1]+=av.w*bv.y; cm[3][2]+=av.w*bv.z; cm[3][3]+=av.w*bv.w;
}

// one k4-step of a 4x4-tile GEMM with row-major A segments; named locals only
__device__ __forceinline__ void gemm_step4(float (&cm)[4][4],
    const float4& A0, const float4& A1, const float4& A2, const float4& A3,
    const float4& B0, const float4& B1, const float4& B2, const float4& B3){
  fma16(cm, make_float4(A0.x,A1.x,A2.x,A3.x), B0);
  fma16(cm, make_float4(A0.y,A1.y,A2.y,A3.y), B1);
  fma16(cm, make_float4(A0.z,A1.z,A2.z,A3.z), B2);
  fma16(cm, make_float4(A0.w,A1.w,A2.w,A3.w), B3);
}

// ---------------- edge sort by dst (counting sort) ----------------
__global__ void k_hist(const int* __restrict__ ei, int* __restrict__ counts){
  int e = blockIdx.x*256 + threadIdx.x;
  if (e < EE) atomicAdd(&counts[ei[EE+e]], 1);
}

__global__ void k_scan(const int* __restrict__ counts, int* __restrict__ offsets){
  __shared__ int part[256];
  __shared__ int partx[257];
  int t = threadIdx.x;
  const int chunk = (NN + 255)/256;   // 10
  int base = t*chunk;
  int s = 0;
  for (int i=0;i<chunk;i++){ int idx=base+i; if (idx<NN) s += counts[idx]; }
  part[t] = s;
  __syncthreads();
  if (t==0){ int acc=0; for (int i=0;i<256;i++){ partx[i]=acc; acc+=part[i]; } partx[256]=acc; }
  __syncthreads();
  int acc = partx[t];
  for (int i=0;i<chunk;i++){ int idx=base+i; if (idx<NN){ offsets[idx]=acc; acc+=counts[idx]; } }
  if (t==0) offsets[NN] = partx[256];
}

__global__ void k_scatter(const int* __restrict__ ei, const int* __restrict__ offsets,
                          int* __restrict__ cursor, int* __restrict__ order){
  int e = blockIdx.x*256 + threadIdx.x;
  if (e < EE){
    int d = ei[EE+e];
    int p = atomicAdd(&cursor[d], 1);
    order[offsets[d]+p] = e;
  }
}

// ---------------- init x: only l=0 row populated ----------------
__global__ void k_init_x(const int* __restrict__ zn, const float* __restrict__ atom_emb,
                         float* __restrict__ x){
  int idx = blockIdx.x*256 + threadIdx.x;
  int n = idx / (LL*CC);
  int r = idx - n*(LL*CC);
  float v = 0.0f;
  if (r < CC) v = atom_emb[zn[n]*CC + r];
  x[idx] = v;
}

// ---------------- edge scalar features -> rad0, rad1 ----------------
__global__ __launch_bounds__(256)
void k_edge(const int* __restrict__ ei, const int* __restrict__ zn,
            const float* __restrict__ pos,
            const float* __restrict__ src_emb, const float* __restrict__ dst_emb,
            const float* __restrict__ W_e1, const float* __restrict__ W_e2,
            const float* __restrict__ W_rad,
            float* __restrict__ rad0, float* __restrict__ rad1){
  __shared__ float feat[8][EFD];
  __shared__ float efl[8][CC];
  __shared__ float dist[8];
  int t = threadIdx.x;
  int e0 = blockIdx.x*8;
  if (t < 8){
    int e = e0+t;
    int s = ei[e], d = ei[EE+e];
    float dx = pos[s*3]-pos[d*3], dy = pos[s*3+1]-pos[d*3+1], dz = pos[s*3+2]-pos[d*3+2];
    dist[t] = sqrtf(dx*dx+dy*dy+dz*dz);
  }
  __syncthreads();
  const float step = 12.0f/599.0f;
  const float coeff = -0.5f/((2.0f*step)*(2.0f*step));
  for (int eidx=0; eidx<8; ++eidx){
    int e = e0+eidx;
    int zs = zn[ei[e]], zd = zn[ei[EE+e]];
    float de = dist[eidx];
    for (int k=t;k<EFD;k+=256){
      float v;
      if (k < NBASIS){ float u = de - k*step; v = expf(coeff*u*u); }
      else if (k < NBASIS+CC) v = src_emb[zs*CC + (k-NBASIS)];
      else v = dst_emb[zd*CC + (k-NBASIS-CC)];
      feat[eidx][k] = v;
    }
  }
  __syncthreads();
  int eidx = t>>5;
  int c0 = (t&31)*4;
  float a0=0,a1=0,a2=0,a3=0;
  for (int k=0;k<EFD;k++){
    float f = feat[eidx][k];
    const float4 w = *(const float4*)&W_e1[k*CC + c0];
    a0 += f*w.x; a1 += f*w.y; a2 += f*w.z; a3 += f*w.w;
  }
  efl[eidx][c0]=silu_f(a0); efl[eidx][c0+1]=silu_f(a1); efl[eidx][c0+2]=silu_f(a2); efl[eidx][c0+3]=silu_f(a3);
  __syncthreads();
  a0=a1=a2=a3=0;
  for (int k=0;k<CC;k++){
    float f = efl[eidx][k];
    const float4 w = *(const float4*)&W_e2[k*CC+c0];
    a0 += f*w.x; a1 += f*w.y; a2 += f*w.z; a3 += f*w.w;
  }
  __syncthreads();
  efl[eidx][c0]=silu_f(a0); efl[eidx][c0+1]=silu_f(a1); efl[eidx][c0+2]=silu_f(a2); efl[eidx][c0+3]=silu_f(a3);
  __syncthreads();
  #pragma unroll
  for (int l=0;l<2;l++){
    const float* Wr = W_rad + l*CC*CC;
    float r0=0,r1=0,r2=0,r3=0;
    for (int k=0;k<CC;k++){
      float f = efl[eidx][k];
      const float4 w = *(const float4*)&Wr[k*CC+c0];
      r0+=f*w.x; r1+=f*w.y; r2+=f*w.z; r3+=f*w.w;
    }
    float* out = l ? rad1 : rad0;
    *(float4*)&out[(e0+eidx)*CC + c0] = make_float4(r0,r1,r2,r3);
  }
}

// ---------------- equivariant RMS norm -> h ----------------
__global__ __launch_bounds__(256)
void k_rms(const float* __restrict__ x, const float* __restrict__ gamma, float* __restrict__ h){
  __shared__ float xs[LL][CC];
  __shared__ float ps[2][CC];
  int t = threadIdx.x, n = blockIdx.x;
  const float* xr = x + n*LL*CC;
  {
    float4* xs4 = (float4*)&xs[0][0];
    const float4* x4 = (const float4*)xr;
    for (int i=t;i<LL*CC/4;i+=256) xs4[i]=x4[i];
  }
  __syncthreads();
  int c = t&127, hf = t>>7;
  int r0 = hf?13:0, r1 = hf?LL:13;
  float s=0;
  for (int r=r0;r<r1;r++){ float v = xs[r][c]; s += v*v; }
  ps[hf][c]=s;
  __syncthreads();
  float rn = 1.0f/sqrtf((ps[0][c]+ps[1][c])*(1.0f/(float)LL) + 1e-6f);
  float g = gamma[c]*rn;
  float* hr = h + n*LL*CC;
  for (int r=r0;r<r1;r++) hr[r*CC+c] = xs[r][c]*g;
}

// ---------------- attention logits ----------------
__global__ __launch_bounds__(256)
void k_logits(const int* __restrict__ ei, const float* __restrict__ h,
              const float* __restrict__ rad, const float* __restrict__ wig,
              const float* __restrict__ Wa1, const float* __restrict__ wa2,
              float* __restrict__ logits){
  __shared__ float w0[8][LL];
  __shared__ float m0[8][CC];
  __shared__ float aS[8][HH*AA];
  int t = threadIdx.x;
  int e0 = blockIdx.x*8;
  for (int i=t;i<8*LL;i+=256){
    int eidx = i/LL, j = i - eidx*LL;
    w0[eidx][j] = wig[(e0+eidx)*625 + j];
  }
  __syncthreads();
  {
    int c = t&127, eg = t>>7;
    for (int j=0;j<4;j++){
      int e = e0 + eg*4 + j;
      int s = ei[e], d = ei[EE+e];
      const float* hs = h + s*LL*CC + c;
      const float* hd = h + d*LL*CC + c;
      float acc = 0;
      #pragma unroll
      for (int r=0;r<LL;r++) acc += w0[eg*4+j][r]*(hs[r*CC]+hd[r*CC]);
      m0[eg*4+j][c] = acc*rad[e*CC+c];
    }
  }
  __syncthreads();
  float accA[16];
  #pragma unroll
  for (int i=0;i<16;i++) accA[i]=0;
  for (int k=0;k<CC;k++){
    float wv0 = Wa1[k*512 + t];
    float wv1 = Wa1[k*512 + 256 + t];
    #pragma unroll
    for (int e=0;e<8;e++){
      float mv = m0[e][k];
      accA[e*2]   += mv*wv0;
      accA[e*2+1] += mv*wv1;
    }
  }
  #pragma unroll
  for (int e=0;e<8;e++){ aS[e][t]=silu_f(accA[e*2]); aS[e][256+t]=silu_f(accA[e*2+1]); }
  __syncthreads();
  if (t < 64){
    int eidx = t>>3, hh2 = t&7;
    float lg = 0;
    #pragma unroll
    for (int a=0;a<AA;a++) lg += aS[eidx][hh2*AA+a]*wa2[hh2*AA+a];
    logits[(e0+eidx)*HH + hh2] = lg;
  }
}

// ---------------- per-dst softmax (one wave, 8 sub-lanes per head) ----------------
__global__ void k_softmax(const float* __restrict__ logits, const int* __restrict__ order,
                          const int* __restrict__ offsets, float* __restrict__ alpha){
  int n = blockIdx.x, t = threadIdx.x;
  int head = t & 7, sub = t >> 3;
  int b = offsets[n], cnt = offsets[n+1]-b;
  float m = -1e30f;
  for (int i=sub;i<cnt;i+=8) m = fmaxf(m, logits[order[b+i]*HH + head]);
  m = fmaxf(m, __shfl_xor(m, 8));
  m = fmaxf(m, __shfl_xor(m, 16));
  m = fmaxf(m, __shfl_xor(m, 32));
  float z = 0;
  for (int i=sub;i<cnt;i+=8) z += expf(logits[order[b+i]*HH + head] - m);
  z += __shfl_xor(z, 8);
  z += __shfl_xor(z, 16);
  z += __shfl_xor(z, 32);
  float inv = 1.0f/(z + 1e-9f);
  for (int i=sub;i<cnt;i+=8){
    int e = order[b+i];
    alpha[e*HH+head] = expf(logits[e*HH+head]-m)*inv;
  }
}

// ---------------- heavy attention: one block per destination node ----------------
// Per-head hoist of W_val AND W_out out of the edge sum:
//   u_e = WigT_e @ ((Wig_e @ (h[s]+h[d])) . rad_e)          (160K MAC/edge)
//   U_h = sum_e alpha[e][h] * u_e                            (25.6K MAC/edge, in REGISTERS)
//   o[:, h*16:+16] = U_h @ Wv[:, h*16:+16]  (per node)       then o @ Wo, += x
// Thread (rt,dt): h=rt, cols d0=dt*4; U[25][4] fully unrolled (static idx, rule #20).
__global__ __launch_bounds__(256,2)
void k_attn(const int* __restrict__ ei, const float* __restrict__ h,
            const float* __restrict__ wig_g, const float* __restrict__ rad,
            const float* __restrict__ alpha,
            const float* __restrict__ Wv, const float* __restrict__ Wo,
            const int* __restrict__ order, const int* __restrict__ offsets,
            float* __restrict__ x){
  __shared__ __align__(16) float smem[13568];   // 54272 B
  float* wigA = smem;          // [28][32]  wigA[k][i] = wig[i][k]  (GEMM1 A, bcast b128)
  float* wigB = smem + 896;    // [28][32]  wigB[k][l] = wig[k][l]  (GEMM3 A)
  float* hsum = smem + 1792;   // [28][128] rows 25-27 zero
  float* msg  = smem + 5376;   // [32][128] GEMM1 out; finale o_full; rows 25+ stay 0
  float* u    = smem + 9472;   // [32][128] GEMM3 out
  float* Uc   = smem;          // finale alias [8][5][128] = 5120 floats (< 5376)

  int n = blockIdx.x;
  int b = offsets[n];
  int cnt = offsets[n+1]-b;
  if (cnt == 0) return;
  int t = threadIdx.x;
  int dt = t & 31, rt = t >> 5;
  int d0 = dt*4, i0 = rt*4;

  float U[25][4];
  #pragma unroll
  for (int l=0;l<25;l++){ U[l][0]=0;U[l][1]=0;U[l][2]=0;U[l][3]=0; }

  // zero pads once (stores below only touch r,c < 25 regions)
  for (int i=t;i<896;i+=256){ wigA[i]=0.0f; wigB[i]=0.0f; }
  for (int i=t;i<384;i+=256) hsum[3200+i]=0.0f;

  int e = order[b];
  float4 ph0=make_float4(0,0,0,0), ph1=ph0, ph2=ph0, ph3=ph0;
  float pw0=0, pw1=0, pw2=0;
  {
    int s = ei[e], d = ei[EE+e];
    const float4* hs4 = (const float4*)(h + (size_t)s*LL*CC);
    const float4* hd4 = (const float4*)(h + (size_t)d*LL*CC);
    const float*  we  = wig_g + (size_t)e*625;
    float4 a, bb;
    a=hs4[t];     bb=hd4[t];     ph0=make_float4(a.x+bb.x,a.y+bb.y,a.z+bb.z,a.w+bb.w);
    a=hs4[t+256]; bb=hd4[t+256]; ph1=make_float4(a.x+bb.x,a.y+bb.y,a.z+bb.z,a.w+bb.w);
    a=hs4[t+512]; bb=hd4[t+512]; ph2=make_float4(a.x+bb.x,a.y+bb.y,a.z+bb.z,a.w+bb.w);
    if (t<32){ a=hs4[t+768]; bb=hd4[t+768]; ph3=make_float4(a.x+bb.x,a.y+bb.y,a.z+bb.z,a.w+bb.w); }
    pw0 = we[t];
    pw1 = we[t+256];
    if (t<113) pw2 = we[t+512];
  }
  __syncthreads();   // zero-init visible
  {
    { int i2=t;      *(float4*)&hsum[(i2>>5)*128 + (i2&31)*4] = ph0; }
    { int i2=t+256;  *(float4*)&hsum[(i2>>5)*128 + (i2&31)*4] = ph1; }
    { int i2=t+512;  *(float4*)&hsum[(i2>>5)*128 + (i2&31)*4] = ph2; }
    if (t<32){ int i2=t+768; *(float4*)&hsum[(i2>>5)*128 + (i2&31)*4] = ph3; }
    { int i=t;     int r=i/25, c=i-25*r; wigA[c*32+r]=pw0; wigB[r*32+c]=pw0; }
    { int i=t+256; int r=i/25, c=i-25*r; wigA[c*32+r]=pw1; wigB[r*32+c]=pw1; }
    if (t<113){ int i=t+512; int r=i/25, c=i-25*r; wigA[c*32+r]=pw2; wigB[r*32+c]=pw2; }
  }
  __syncthreads();

  for (int idx=0; idx<cnt; ++idx){
    float4 rad4 = *(const float4*)&rad[(size_t)e*CC + d0];
    float  alf  = alpha[(size_t)e*HH + rt];
    int e_next = (idx+1<cnt) ? order[b+idx+1] : e;

    // GEMM1: msg[i][c] = (sum_k wig[i][k]*hsum[k][c]) * rad[c]
    {
      float cm[4][4];
      #pragma unroll
      for (int m=0;m<4;m++){ cm[m][0]=0; cm[m][1]=0; cm[m][2]=0; cm[m][3]=0; }
      #pragma unroll 4
      for (int k=0;k<28;k++){
        float4 av = *(const float4*)&wigA[k*32+i0];
        float4 bv = *(const float4*)&hsum[k*128+d0];
        fma16(cm, av, bv);
      }
      #pragma unroll
      for (int m=0;m<4;m++)
        *(float4*)&msg[(i0+m)*128+d0] = make_float4(cm[m][0]*rad4.x, cm[m][1]*rad4.y,
                                                    cm[m][2]*rad4.z, cm[m][3]*rad4.w);
    }
    __syncthreads();   // b1: msg ready, hsum/wigA dead

    // issue next edge's global loads (latency hides under GEMM3)
    {
      int s = ei[e_next], d = ei[EE+e_next];
      const float4* hs4 = (const float4*)(h + (size_t)s*LL*CC);
      const float4* hd4 = (const float4*)(h + (size_t)d*LL*CC);
      const float*  we  = wig_g + (size_t)e_next*625;
      float4 a, bb;
      a=hs4[t];     bb=hd4[t];     ph0=make_float4(a.x+bb.x,a.y+bb.y,a.z+bb.z,a.w+bb.w);
      a=hs4[t+256]; bb=hd4[t+256]; ph1=make_float4(a.x+bb.x,a.y+bb.y,a.z+bb.z,a.w+bb.w);
      a=hs4[t+512]; bb=hd4[t+512]; ph2=make_float4(a.x+bb.x,a.y+bb.y,a.z+bb.z,a.w+bb.w);
      if (t<32){ a=hs4[t+768]; bb=hd4[t+768]; ph3=make_float4(a.x+bb.x,a.y+bb.y,a.z+bb.z,a.w+bb.w); }
      pw0 = we[t];
      pw1 = we[t+256];
      if (t<113) pw2 = we[t+512];
    }

    // GEMM3: u[l][c] = sum_k wig[k][l]*msg[k][c]
    {
      float cm[4][4];
      #pragma unroll
      for (int m=0;m<4;m++){ cm[m][0]=0; cm[m][1]=0; cm[m][2]=0; cm[m][3]=0; }
      #pragma unroll 4
      for (int k=0;k<28;k++){
        float4 av = *(const float4*)&wigB[k*32+i0];
        float4 bv = *(const float4*)&msg[k*128+d0];
        fma16(cm, av, bv);
      }
      #pragma unroll
      for (int m=0;m<4;m++)
        *(float4*)&u[(i0+m)*128+d0] = make_float4(cm[m][0], cm[m][1], cm[m][2], cm[m][3]);
    }
    __syncthreads();   // b2: u ready, wigB dead

    // retire staging into LDS (hsum/wig dead; next GEMM1 waits at b3)
    {
      { int i2=t;      *(float4*)&hsum[(i2>>5)*128 + (i2&31)*4] = ph0; }
      { int i2=t+256;  *(float4*)&hsum[(i2>>5)*128 + (i2&31)*4] = ph1; }
      { int i2=t+512;  *(float4*)&hsum[(i2>>5)*128 + (i2&31)*4] = ph2; }
      if (t<32){ int i2=t+768; *(float4*)&hsum[(i2>>5)*128 + (i2&31)*4] = ph3; }
      { int i=t;     int r=i/25, c=i-25*r; wigA[c*32+r]=pw0; wigB[r*32+c]=pw0; }
      { int i=t+256; int r=i/25, c=i-25*r; wigA[c*32+r]=pw1; wigB[r*32+c]=pw1; }
      if (t<113){ int i=t+512; int r=i/25, c=i-25*r; wigA[c*32+r]=pw2; wigB[r*32+c]=pw2; }
    }

    // U update: U[l][j] += alpha[e][rt] * u[l][d0+j]
    #pragma unroll
    for (int l=0;l<25;l++){
      float4 uv = *(const float4*)&u[l*128 + d0];
      U[l][0]+=alf*uv.x; U[l][1]+=alf*uv.y; U[l][2]+=alf*uv.z; U[l][3]+=alf*uv.w;
    }
    e = e_next;
    __syncthreads();   // b3: staging complete, u dead
  }

  // ---- finale: o[l][hv] = sum_c U[hv>>4][l][c] * Wv[c][hv], chunked 5 l-rows ----
  #pragma unroll
  for (int ch=0; ch<5; ++ch){
    #pragma unroll
    for (int ls=0; ls<5; ++ls)
      *(float4*)&Uc[(rt*5+ls)*128 + d0] =
        make_float4(U[ch*5+ls][0], U[ch*5+ls][1], U[ch*5+ls][2], U[ch*5+ls][3]);
    __syncthreads();
    {
      int col = t & 127;
      int lr  = t >> 7;            // 0 or 1
      int hh  = col >> 4;
      const float* U0 = &Uc[(hh*5 + lr  )*128];
      const float* U1 = &Uc[(hh*5 + lr+2)*128];
      const float* U2 = &Uc[(hh*5 + (lr? 0:4))*128];   // dummy row for lr==1
      float o0=0, o1=0, o2=0;
      #pragma unroll 8
      for (int c2=0;c2<128;c2++){
        float wv = Wv[c2*128 + col];
        o0 += U0[c2]*wv; o1 += U1[c2]*wv; o2 += U2[c2]*wv;
      }
      msg[(ch*5+lr  )*128 + col] = o0;
      msg[(ch*5+lr+2)*128 + col] = o1;
      if (lr==0) msg[(ch*5+4)*128 + col] = o2;
    }
    __syncthreads();
  }

  // GEMM4: out[i][c'] = sum_d o_full[i][d]*Wo[d][c']; residual into x
  {
    float co[4][4];
    #pragma unroll
    for (int m=0;m<4;m++){ co[m][0]=0; co[m][1]=0; co[m][2]=0; co[m][3]=0; }
    for (int k4=0;k4<CC;k4+=4){
      float4 A0 = *(const float4*)&msg[(i0+0)*128+k4];
      float4 A1 = *(const float4*)&msg[(i0+1)*128+k4];
      float4 A2 = *(const float4*)&msg[(i0+2)*128+k4];
      float4 A3 = *(const float4*)&msg[(i0+3)*128+k4];
      float4 B0 = *(const float4*)&Wo[(k4+0)*CC + d0];
      float4 B1 = *(const float4*)&Wo[(k4+1)*CC + d0];
      float4 B2 = *(const float4*)&Wo[(k4+2)*CC + d0];
      float4 B3 = *(const float4*)&Wo[(k4+3)*CC + d0];
      gemm_step4(co, A0,A1,A2,A3, B0,B1,B2,B3);
    }
    #pragma unroll
    for (int m=0;m<4;m++){
      int i = i0+m;
      if (i < LL){
        float4 xv = *(float4*)&x[(size_t)n*LL*CC + i*CC + d0];
        xv.x += co[m][0]; xv.y += co[m][1]; xv.z += co[m][2]; xv.w += co[m][3];
        *(float4*)&x[(size_t)n*LL*CC + i*CC + d0] = xv;
      }
    }
  }
}

// ---------------- gated FFN (rmsnorm fused) ----------------
__global__ __launch_bounds__(256)
void k_ffn(float* __restrict__ x, const float* __restrict__ gamma,
           const float* __restrict__ Wf1, const float* __restrict__ Wg,
           const float* __restrict__ Wf2){
  __shared__ float xs[LL][CC];
  __shared__ float tT[CC][32];   // hT then hidT
  __shared__ float gs[FF];
  __shared__ float ps[2][CC];
  int t = threadIdx.x, n = blockIdx.x;
  float* xr = x + n*LL*CC;
  {
    float4* xs4 = (float4*)&xs[0][0];
    const float4* x4 = (const float4*)xr;
    for (int i=t;i<LL*CC/4;i+=256) xs4[i]=x4[i];
  }
  __syncthreads();
  int c = t&127, hf = t>>7;
  int r0 = hf?13:0, r1 = hf?LL:13;
  {
    float s=0;
    for (int r=r0;r<r1;r++){ float v=xs[r][c]; s += v*v; }
    ps[hf][c]=s;
  }
  __syncthreads();
  float rn = 1.0f/sqrtf((ps[0][c]+ps[1][c])*(1.0f/(float)LL) + 1e-6f);
  float gm = gamma[c]*rn;
  for (int r=r0;r<r1;r++) tT[c][r] = xs[r][c]*gm;
  if (hf==0){ for (int r=LL;r<32;r++) tT[c][r] = 0.0f; }
  __syncthreads();
  if (t < FF){
    float gv=0;
    for (int k=0;k<CC;k++) gv += tT[k][0]*Wg[k*FF+t];
    gs[t] = silu_f(gv);
  }
  int dt=t&31, rt=t>>5, d0=dt*4, i0=rt*4;
  float cm[4][4];
  #pragma unroll
  for (int m=0;m<4;m++){ cm[m][0]=0; cm[m][1]=0; cm[m][2]=0; cm[m][3]=0; }
  #pragma unroll 4
  for (int k=0;k<CC;k++){
    float4 av = *(const float4*)&tT[k][i0];
    float4 bv = *(const float4*)&Wf1[k*FF+d0];
    fma16(cm, av, bv);
  }
  __syncthreads();
  #pragma unroll
  for (int j=0;j<4;j++){
    float gj = gs[d0+j];
    *(float4*)&tT[d0+j][i0] = make_float4(cm[0][j]*gj, cm[1][j]*gj, cm[2][j]*gj, cm[3][j]*gj);
  }
  __syncthreads();
  float co[4][4];
  #pragma unroll
  for (int m=0;m<4;m++){ co[m][0]=0; co[m][1]=0; co[m][2]=0; co[m][3]=0; }
  #pragma unroll 4
  for (int k=0;k<FF;k++){
    float4 av = *(const float4*)&tT[k][i0];
    float4 bv = *(const float4*)&Wf2[k*CC+d0];
    fma16(co, av, bv);
  }
  #pragma unroll
  for (int m=0;m<4;m++){
    int i=i0+m;
    if (i<LL){
      float4 xv = *(float4*)&xs[i][d0];
      xv.x+=co[m][0]; xv.y+=co[m][1]; xv.z+=co[m][2]; xv.w+=co[m][3];
      *(float4*)&xr[i*CC+d0] = xv;
    }
  }
}

extern "C" void kernel_launch(void* const* d_in, const int* in_sizes, int n_in,
                              void* d_out, int out_size, void* d_ws, size_t ws_size,
                              hipStream_t stream){
  const int*   zn       = (const int*)  d_in[0];
  const float* pos      = (const float*)d_in[1];
  const int*   ei       = (const int*)  d_in[2];
  const float* wig      = (const float*)d_in[3];
  const float* atom_emb = (const float*)d_in[4];
  const float* src_emb  = (const float*)d_in[5];
  const float* dst_emb  = (const float*)d_in[6];
  const float* W_e1     = (const float*)d_in[7];
  const float* W_e2     = (const float*)d_in[8];
  const float* g_attn   = (const float*)d_in[9];
  const float* g_ffn    = (const float*)d_in[10];
  const float* W_rad    = (const float*)d_in[11];
  const float* W_a1     = (const float*)d_in[12];
  const float* w_a2     = (const float*)d_in[13];
  const float* W_val    = (const float*)d_in[14];
  const float* W_out    = (const float*)d_in[15];
  const float* W_f1     = (const float*)d_in[16];
  const float* W_g      = (const float*)d_in[17];
  const float* W_f2     = (const float*)d_in[18];
  float* x = (float*)d_out;

  char* w = (char*)d_ws;
  float* h      = (float*)w;  w += (size_t)NN*LL*CC*4;
  float* rad0   = (float*)w;  w += (size_t)EE*CC*4;
  float* rad1   = (float*)w;  w += (size_t)EE*CC*4;
  float* logits = (float*)w;  w += (size_t)EE*HH*4;
  float* alpha  = (float*)w;  w += (size_t)EE*HH*4;
  int* order    = (int*)w;    w += (size_t)EE*4;
  int* counts   = (int*)w;    w += (size_t)NN*4;
  int* offsets  = (int*)w;    w += (size_t)(NN+4)*4;
  int* cursor   = (int*)w;    w += (size_t)NN*4;

  hipMemsetAsync(counts, 0, NN*4, stream);
  hipMemsetAsync(cursor, 0, NN*4, stream);
  k_hist   <<<(EE+255)/256,256,0,stream>>>(ei, counts);
  k_scan   <<<1,256,0,stream>>>(counts, offsets);
  k_scatter<<<(EE+255)/256,256,0,stream>>>(ei, offsets, cursor, order);
  k_edge   <<<EE/8,256,0,stream>>>(ei, zn, pos, src_emb, dst_emb, W_e1, W_e2, W_rad, rad0, rad1);
  k_init_x <<<(NN*LL*CC)/256,256,0,stream>>>(zn, atom_emb, x);

  for (int l=0;l<2;l++){
    const float* radl = l? rad1:rad0;
    k_rms    <<<NN,256,0,stream>>>(x, g_attn + l*CC, h);
    k_logits <<<EE/8,256,0,stream>>>(ei, h, radl, wig, W_a1 + l*CC*HH*AA, w_a2 + l*HH*AA, logits);
    k_softmax<<<NN,64,0,stream>>>(logits, order, offsets, alpha);
    k_attn   <<<NN,256,0,stream>>>(ei, h, wig, radl, alpha, W_val + l*CC*HH*VV,
                                   W_out + l*HH*VV*CC, order, offsets, x);
    k_ffn    <<<NN,256,0,stream>>>(x, g_ffn + l*CC, W_f1 + l*CC*FF, W_g + l*CC*FF, W_f2 + l*FF*CC);
  }
}

// Round 6
// 2305.989 us; speedup vs baseline: 25.5492x; 1.3133x over previous
//
#include <hip/hip_runtime.h>
#include <math.h>

#define NN 2500
#define EE 50000
#define CC 128
#define LL 25
#define HH 8
#define AA 64
#define VV 16
#define FF 128
#define NBASIS 600
#define EFD (NBASIS + 2*CC)   // 856
#define WB 32                 // edges per k_edge block
#define WIN 32                // gaussian window width

__device__ __forceinline__ float silu_f(float x){ return x / (1.0f + expf(-x)); }

__device__ __forceinline__ void fma16(float (&cm)[4][4], const float4& av, const float4& bv){
  cm[0][0]+=av.x*bv.x; cm[0][1]+=av.x*bv.y; cm[0][2]+=av.x*bv.z; cm[0][3]+=av.x*bv.w;
  cm[1][0]+=av.y*bv.x; cm[1][1]+=av.y*bv.y; cm[1][2]+=av.y*bv.z; cm[1][3]+=av.y*bv.w;
  cm[2][0]+=av.z*bv.x; cm[2][1]+=av.z*bv.y; cm[2][2]+=av.z*bv.z; cm[2][3]+=av.z*bv.w;
  cm[3][0]+=av.w*bv.x; cm[3][1]+=av.w*bv.y; cm[3][2]+=av.w*bv.z; cm[3][3]+=av.w*bv.w;
}

// one k4-step of a 4x4-tile GEMM with row-major A segments; named locals only
__device__ __forceinline__ void gemm_step4(float (&cm)[4][4],
    const float4& A0, const float4& A1, const float4& A2, const float4& A3,
    const float4& B0, const float4& B1, const float4& B2, const float4& B3){
  fma16(cm, make_float4(A0.x,A1.x,A2.x,A3.x), B0);
  fma16(cm, make_float4(A0.y,A1.y,A2.y,A3.y), B1);
  fma16(cm, make_float4(A0.z,A1.z,A2.z,A3.z), B2);
  fma16(cm, make_float4(A0.w,A1.w,A2.w,A3.w), B3);
}

// ---------------- edge sort by dst (counting sort) ----------------
__global__ void k_hist(const int* __restrict__ ei, int* __restrict__ counts){
  int e = blockIdx.x*256 + threadIdx.x;
  if (e < EE) atomicAdd(&counts[ei[EE+e]], 1);
}

__global__ void k_scan(const int* __restrict__ counts, int* __restrict__ offsets){
  __shared__ int part[256];
  __shared__ int partx[257];
  int t = threadIdx.x;
  const int chunk = (NN + 255)/256;   // 10
  int base = t*chunk;
  int s = 0;
  for (int i=0;i<chunk;i++){ int idx=base+i; if (idx<NN) s += counts[idx]; }
  part[t] = s;
  __syncthreads();
  if (t==0){ int acc=0; for (int i=0;i<256;i++){ partx[i]=acc; acc+=part[i]; } partx[256]=acc; }
  __syncthreads();
  int acc = partx[t];
  for (int i=0;i<chunk;i++){ int idx=base+i; if (idx<NN){ offsets[idx]=acc; acc+=counts[idx]; } }
  if (t==0) offsets[NN] = partx[256];
}

__global__ void k_scatter(const int* __restrict__ ei, const int* __restrict__ offsets,
                          int* __restrict__ cursor, int* __restrict__ order){
  int e = blockIdx.x*256 + threadIdx.x;
  if (e < EE){
    int d = ei[EE+e];
    int p = atomicAdd(&cursor[d], 1);
    order[offsets[d]+p] = e;
  }
}

// ---------------- init x: only l=0 row populated ----------------
__global__ void k_init_x(const int* __restrict__ zn, const float* __restrict__ atom_emb,
                         float* __restrict__ x){
  int idx = blockIdx.x*256 + threadIdx.x;
  int n = idx / (LL*CC);
  int r = idx - n*(LL*CC);
  float v = 0.0f;
  if (r < CC) v = atom_emb[zn[n]*CC + r];
  x[idx] = v;
}

// ---------------- precompute element-embedding @ W_e1 blocks ----------------
// embw[0..89][c]   = src_emb[z] @ W_e1[600:728]
// embw[90..179][c] = dst_emb[z] @ W_e1[728:856]
__global__ __launch_bounds__(256)
void k_embmm(const float* __restrict__ src_emb, const float* __restrict__ dst_emb,
             const float* __restrict__ W_e1, float* __restrict__ embw){
  int z = blockIdx.x;          // 0..89
  int t = threadIdx.x;
  int c = t & 127, half = t >> 7;
  const float* emb = half ? dst_emb : src_emb;
  const float* W = W_e1 + (size_t)(NBASIS + half*CC)*CC;
  float acc = 0;
  for (int k=0;k<CC;k++) acc += emb[z*CC+k]*W[k*CC+c];
  embw[((size_t)half*90 + z)*CC + c] = acc;
}

// ---------------- edge scalar features -> rad0, rad1 (windowed basis) ----------------
// Gaussian basis is ~zero outside |d - o_k| > 0.31 (32 offsets): truncation ~1e-13.
// 32 edges/block; W_e2 + both W_rad applied as 32x128x128 tile GEMMs.
__global__ __launch_bounds__(256)
void k_edge(const int* __restrict__ ei, const int* __restrict__ zn,
            const float* __restrict__ pos, const float* __restrict__ embw,
            const float* __restrict__ W_e1, const float* __restrict__ W_e2,
            const float* __restrict__ W_rad,
            float* __restrict__ rad0, float* __restrict__ rad1){
  __shared__ float bw[WIN*WB];      // bw[kk][eidx]
  __shared__ float ef [WB*CC];
  __shared__ float ef2[WB*CC];
  __shared__ float dL[WB];
  __shared__ int   k0L[WB], zsL[WB], zdL[WB];
  int t = threadIdx.x;
  int e0 = blockIdx.x*WB;
  const float step = 12.0f/599.0f;
  const float coeff = -0.5f/((2.0f*step)*(2.0f*step));

  if (t < WB){
    int e = e0 + t;
    float dd = 1e15f; int zs=0, zd=0;
    if (e < EE){
      int s = ei[e], d2 = ei[EE+e];
      float dx = pos[s*3]-pos[d2*3], dy = pos[s*3+1]-pos[d2*3+1], dz = pos[s*3+2]-pos[d2*3+2];
      dd = sqrtf(dx*dx+dy*dy+dz*dz);
      zs = zn[s]; zd = zn[d2];
    }
    dL[t] = dd;
    int kk0 = (int)floorf(dd/step + 0.5f);
    if (kk0 < 0) kk0 = 0;
    if (kk0 > NBASIS-1) kk0 = NBASIS-1;
    k0L[t] = kk0;
    zsL[t] = zs; zdL[t] = zd;
  }
  __syncthreads();
  {
    int eidx = t & 31, kb = t >> 5;
    float dd = dL[eidx]; int kk0 = k0L[eidx];
    #pragma unroll
    for (int p=0;p<4;p++){
      int kk = kb + p*8;
      int k = kk0 - 15 + kk;
      float b = 0.0f;
      if (k >= 0 && k < NBASIS){ float u = dd - k*step; b = expf(coeff*u*u); }
      bw[kk*WB + eidx] = b;
    }
  }
  __syncthreads();

  // step1: ef = silu(windowed-basis @ W1a + srcW[zs] + dstW[zd]); 16 cols/thread
  {
    int eidx = t >> 3, cg = t & 7;
    int c0 = cg*16;
    int kk0 = k0L[eidx];
    float4 f0 = make_float4(0,0,0,0), f1=f0, f2=f0, f3=f0;
    #pragma unroll 4
    for (int kk=0;kk<WIN;kk++){
      float b = bw[kk*WB + eidx];
      int k = kk0 - 15 + kk;
      k = k < 0 ? 0 : (k > NBASIS-1 ? NBASIS-1 : k);
      const float* wr = &W_e1[(size_t)k*CC + c0];
      float4 w0 = *(const float4*)&wr[0];
      float4 w1 = *(const float4*)&wr[4];
      float4 w2 = *(const float4*)&wr[8];
      float4 w3 = *(const float4*)&wr[12];
      f0.x+=b*w0.x; f0.y+=b*w0.y; f0.z+=b*w0.z; f0.w+=b*w0.w;
      f1.x+=b*w1.x; f1.y+=b*w1.y; f1.z+=b*w1.z; f1.w+=b*w1.w;
      f2.x+=b*w2.x; f2.y+=b*w2.y; f2.z+=b*w2.z; f2.w+=b*w2.w;
      f3.x+=b*w3.x; f3.y+=b*w3.y; f3.z+=b*w3.z; f3.w+=b*w3.w;
    }
    int zs = zsL[eidx], zd = zdL[eidx];
    const float* sw = &embw[(size_t)zs*CC + c0];
    const float* dw = &embw[(size_t)(90+zd)*CC + c0];
    float4 s0=*(const float4*)&sw[0], s1=*(const float4*)&sw[4], s2=*(const float4*)&sw[8], s3=*(const float4*)&sw[12];
    float4 g0=*(const float4*)&dw[0], g1=*(const float4*)&dw[4], g2=*(const float4*)&dw[8], g3=*(const float4*)&dw[12];
    float* er = &ef[eidx*CC + c0];
    *(float4*)&er[0]  = make_float4(silu_f(f0.x+s0.x+g0.x), silu_f(f0.y+s0.y+g0.y), silu_f(f0.z+s0.z+g0.z), silu_f(f0.w+s0.w+g0.w));
    *(float4*)&er[4]  = make_float4(silu_f(f1.x+s1.x+g1.x), silu_f(f1.y+s1.y+g1.y), silu_f(f1.z+s1.z+g1.z), silu_f(f1.w+s1.w+g1.w));
    *(float4*)&er[8]  = make_float4(silu_f(f2.x+s2.x+g2.x), silu_f(f2.y+s2.y+g2.y), silu_f(f2.z+s2.z+g2.z), silu_f(f2.w+s2.w+g2.w));
    *(float4*)&er[12] = make_float4(silu_f(f3.x+s3.x+g3.x), silu_f(f3.y+s3.y+g3.y), silu_f(f3.z+s3.z+g3.z), silu_f(f3.w+s3.w+g3.w));
  }
  __syncthreads();

  int dt = t & 31, rt = t >> 5;
  int d0 = dt*4, m0 = rt*4;

  // step2: ef2 = silu(ef @ W_e2)
  {
    float cm[4][4];
    #pragma unroll
    for (int m=0;m<4;m++){ cm[m][0]=0; cm[m][1]=0; cm[m][2]=0; cm[m][3]=0; }
    for (int k4=0;k4<CC;k4+=4){
      float4 A0 = *(const float4*)&ef[(m0+0)*CC + k4];
      float4 A1 = *(const float4*)&ef[(m0+1)*CC + k4];
      float4 A2 = *(const float4*)&ef[(m0+2)*CC + k4];
      float4 A3 = *(const float4*)&ef[(m0+3)*CC + k4];
      float4 B0 = *(const float4*)&W_e2[(k4+0)*CC + d0];
      float4 B1 = *(const float4*)&W_e2[(k4+1)*CC + d0];
      float4 B2 = *(const float4*)&W_e2[(k4+2)*CC + d0];
      float4 B3 = *(const float4*)&W_e2[(k4+3)*CC + d0];
      gemm_step4(cm, A0,A1,A2,A3, B0,B1,B2,B3);
    }
    #pragma unroll
    for (int m=0;m<4;m++)
      *(float4*)&ef2[(m0+m)*CC + d0] = make_float4(silu_f(cm[m][0]), silu_f(cm[m][1]),
                                                   silu_f(cm[m][2]), silu_f(cm[m][3]));
  }
  __syncthreads();

  // step3: rad_l = ef2 @ W_rad[l], both layers in one pass (shared A reads)
  {
    float c0m[4][4], c1m[4][4];
    #pragma unroll
    for (int m=0;m<4;m++){ c0m[m][0]=0;c0m[m][1]=0;c0m[m][2]=0;c0m[m][3]=0;
                           c1m[m][0]=0;c1m[m][1]=0;c1m[m][2]=0;c1m[m][3]=0; }
    const float* Wr0 = W_rad;
    const float* Wr1 = W_rad + CC*CC;
    for (int k4=0;k4<CC;k4+=4){
      float4 A0 = *(const float4*)&ef2[(m0+0)*CC + k4];
      float4 A1 = *(const float4*)&ef2[(m0+1)*CC + k4];
      float4 A2 = *(const float4*)&ef2[(m0+2)*CC + k4];
      float4 A3 = *(const float4*)&ef2[(m0+3)*CC + k4];
      float4 B0 = *(const float4*)&Wr0[(k4+0)*CC + d0];
      float4 B1 = *(const float4*)&Wr0[(k4+1)*CC + d0];
      float4 B2 = *(const float4*)&Wr0[(k4+2)*CC + d0];
      float4 B3 = *(const float4*)&Wr0[(k4+3)*CC + d0];
      gemm_step4(c0m, A0,A1,A2,A3, B0,B1,B2,B3);
      float4 D0 = *(const float4*)&Wr1[(k4+0)*CC + d0];
      float4 D1 = *(const float4*)&Wr1[(k4+1)*CC + d0];
      float4 D2 = *(const float4*)&Wr1[(k4+2)*CC + d0];
      float4 D3 = *(const float4*)&Wr1[(k4+3)*CC + d0];
      gemm_step4(c1m, A0,A1,A2,A3, D0,D1,D2,D3);
    }
    #pragma unroll
    for (int m=0;m<4;m++){
      int e = e0 + m0 + m;
      if (e < EE){
        *(float4*)&rad0[(size_t)e*CC + d0] = make_float4(c0m[m][0],c0m[m][1],c0m[m][2],c0m[m][3]);
        *(float4*)&rad1[(size_t)e*CC + d0] = make_float4(c1m[m][0],c1m[m][1],c1m[m][2],c1m[m][3]);
      }
    }
  }
}

// ---------------- equivariant RMS norm -> h ----------------
__global__ __launch_bounds__(256)
void k_rms(const float* __restrict__ x, const float* __restrict__ gamma, float* __restrict__ h){
  __shared__ float xs[LL][CC];
  __shared__ float ps[2][CC];
  int t = threadIdx.x, n = blockIdx.x;
  const float* xr = x + n*LL*CC;
  {
    float4* xs4 = (float4*)&xs[0][0];
    const float4* x4 = (const float4*)xr;
    for (int i=t;i<LL*CC/4;i+=256) xs4[i]=x4[i];
  }
  __syncthreads();
  int c = t&127, hf = t>>7;
  int r0 = hf?13:0, r1 = hf?LL:13;
  float s=0;
  for (int r=r0;r<r1;r++){ float v = xs[r][c]; s += v*v; }
  ps[hf][c]=s;
  __syncthreads();
  float rn = 1.0f/sqrtf((ps[0][c]+ps[1][c])*(1.0f/(float)LL) + 1e-6f);
  float g = gamma[c]*rn;
  float* hr = h + n*LL*CC;
  for (int r=r0;r<r1;r++) hr[r*CC+c] = xs[r][c]*g;
}

// ---------------- attention logits ----------------
__global__ __launch_bounds__(256)
void k_logits(const int* __restrict__ ei, const float* __restrict__ h,
              const float* __restrict__ rad, const float* __restrict__ wig,
              const float* __restrict__ Wa1, const float* __restrict__ wa2,
              float* __restrict__ logits){
  __shared__ float w0[8][LL];
  __shared__ float m0[8][CC];
  __shared__ float aS[8][HH*AA];
  int t = threadIdx.x;
  int e0 = blockIdx.x*8;
  for (int i=t;i<8*LL;i+=256){
    int eidx = i/LL, j = i - eidx*LL;
    w0[eidx][j] = wig[(e0+eidx)*625 + j];
  }
  __syncthreads();
  {
    int c = t&127, eg = t>>7;
    for (int j=0;j<4;j++){
      int e = e0 + eg*4 + j;
      int s = ei[e], d = ei[EE+e];
      const float* hs = h + s*LL*CC + c;
      const float* hd = h + d*LL*CC + c;
      float acc = 0;
      #pragma unroll
      for (int r=0;r<LL;r++) acc += w0[eg*4+j][r]*(hs[r*CC]+hd[r*CC]);
      m0[eg*4+j][c] = acc*rad[e*CC+c];
    }
  }
  __syncthreads();
  float accA[16];
  #pragma unroll
  for (int i=0;i<16;i++) accA[i]=0;
  for (int k=0;k<CC;k++){
    float wv0 = Wa1[k*512 + t];
    float wv1 = Wa1[k*512 + 256 + t];
    #pragma unroll
    for (int e=0;e<8;e++){
      float mv = m0[e][k];
      accA[e*2]   += mv*wv0;
      accA[e*2+1] += mv*wv1;
    }
  }
  #pragma unroll
  for (int e=0;e<8;e++){ aS[e][t]=silu_f(accA[e*2]); aS[e][256+t]=silu_f(accA[e*2+1]); }
  __syncthreads();
  if (t < 64){
    int eidx = t>>3, hh2 = t&7;
    float lg = 0;
    #pragma unroll
    for (int a=0;a<AA;a++) lg += aS[eidx][hh2*AA+a]*wa2[hh2*AA+a];
    logits[(e0+eidx)*HH + hh2] = lg;
  }
}

// ---------------- per-dst softmax (one wave, 8 sub-lanes per head) ----------------
__global__ void k_softmax(const float* __restrict__ logits, const int* __restrict__ order,
                          const int* __restrict__ offsets, float* __restrict__ alpha){
  int n = blockIdx.x, t = threadIdx.x;
  int head = t & 7, sub = t >> 3;
  int b = offsets[n], cnt = offsets[n+1]-b;
  float m = -1e30f;
  for (int i=sub;i<cnt;i+=8) m = fmaxf(m, logits[order[b+i]*HH + head]);
  m = fmaxf(m, __shfl_xor(m, 8));
  m = fmaxf(m, __shfl_xor(m, 16));
  m = fmaxf(m, __shfl_xor(m, 32));
  float z = 0;
  for (int i=sub;i<cnt;i+=8) z += expf(logits[order[b+i]*HH + head] - m);
  z += __shfl_xor(z, 8);
  z += __shfl_xor(z, 16);
  z += __shfl_xor(z, 32);
  float inv = 1.0f/(z + 1e-9f);
  for (int i=sub;i<cnt;i+=8){
    int e = order[b+i];
    alpha[e*HH+head] = expf(logits[e*HH+head]-m)*inv;
  }
}

// ---------------- heavy attention: one block per destination node ----------------
__global__ __launch_bounds__(256,2)
void k_attn(const int* __restrict__ ei, const float* __restrict__ h,
            const float* __restrict__ wig_g, const float* __restrict__ rad,
            const float* __restrict__ alpha,
            const float* __restrict__ Wv, const float* __restrict__ Wo,
            const int* __restrict__ order, const int* __restrict__ offsets,
            float* __restrict__ x){
  __shared__ __align__(16) float smem[13568];   // 54272 B
  float* wigA = smem;          // [28][32]  wigA[k][i] = wig[i][k]
  float* wigB = smem + 896;    // [28][32]  wigB[k][l] = wig[k][l]
  float* hsum = smem + 1792;   // [28][128] rows 25-27 zero
  float* msg  = smem + 5376;   // [32][128]
  float* u    = smem + 9472;   // [32][128]
  float* Uc   = smem;          // finale alias [8][5][128]

  int n = blockIdx.x;
  int b = offsets[n];
  int cnt = offsets[n+1]-b;
  if (cnt == 0) return;
  int t = threadIdx.x;
  int dt = t & 31, rt = t >> 5;
  int d0 = dt*4, i0 = rt*4;

  float U[25][4];
  #pragma unroll
  for (int l=0;l<25;l++){ U[l][0]=0;U[l][1]=0;U[l][2]=0;U[l][3]=0; }

  for (int i=t;i<896;i+=256){ wigA[i]=0.0f; wigB[i]=0.0f; }
  for (int i=t;i<384;i+=256) hsum[3200+i]=0.0f;

  int e = order[b];
  float4 ph0=make_float4(0,0,0,0), ph1=ph0, ph2=ph0, ph3=ph0;
  float pw0=0, pw1=0, pw2=0;
  {
    int s = ei[e], d = ei[EE+e];
    const float4* hs4 = (const float4*)(h + (size_t)s*LL*CC);
    const float4* hd4 = (const float4*)(h + (size_t)d*LL*CC);
    const float*  we  = wig_g + (size_t)e*625;
    float4 a, bb;
    a=hs4[t];     bb=hd4[t];     ph0=make_float4(a.x+bb.x,a.y+bb.y,a.z+bb.z,a.w+bb.w);
    a=hs4[t+256]; bb=hd4[t+256]; ph1=make_float4(a.x+bb.x,a.y+bb.y,a.z+bb.z,a.w+bb.w);
    a=hs4[t+512]; bb=hd4[t+512]; ph2=make_float4(a.x+bb.x,a.y+bb.y,a.z+bb.z,a.w+bb.w);
    if (t<32){ a=hs4[t+768]; bb=hd4[t+768]; ph3=make_float4(a.x+bb.x,a.y+bb.y,a.z+bb.z,a.w+bb.w); }
    pw0 = we[t];
    pw1 = we[t+256];
    if (t<113) pw2 = we[t+512];
  }
  __syncthreads();
  {
    { int i2=t;      *(float4*)&hsum[(i2>>5)*128 + (i2&31)*4] = ph0; }
    { int i2=t+256;  *(float4*)&hsum[(i2>>5)*128 + (i2&31)*4] = ph1; }
    { int i2=t+512;  *(float4*)&hsum[(i2>>5)*128 + (i2&31)*4] = ph2; }
    if (t<32){ int i2=t+768; *(float4*)&hsum[(i2>>5)*128 + (i2&31)*4] = ph3; }
    { int i=t;     int r=i/25, c=i-25*r; wigA[c*32+r]=pw0; wigB[r*32+c]=pw0; }
    { int i=t+256; int r=i/25, c=i-25*r; wigA[c*32+r]=pw1; wigB[r*32+c]=pw1; }
    if (t<113){ int i=t+512; int r=i/25, c=i-25*r; wigA[c*32+r]=pw2; wigB[r*32+c]=pw2; }
  }
  __syncthreads();

  for (int idx=0; idx<cnt; ++idx){
    float4 rad4 = *(const float4*)&rad[(size_t)e*CC + d0];
    float  alf  = alpha[(size_t)e*HH + rt];
    int e_next = (idx+1<cnt) ? order[b+idx+1] : e;

    // GEMM1: msg[i][c] = (sum_k wig[i][k]*hsum[k][c]) * rad[c]
    {
      float cm[4][4];
      #pragma unroll
      for (int m=0;m<4;m++){ cm[m][0]=0; cm[m][1]=0; cm[m][2]=0; cm[m][3]=0; }
      #pragma unroll 4
      for (int k=0;k<28;k++){
        float4 av = *(const float4*)&wigA[k*32+i0];
        float4 bv = *(const float4*)&hsum[k*128+d0];
        fma16(cm, av, bv);
      }
      #pragma unroll
      for (int m=0;m<4;m++)
        *(float4*)&msg[(i0+m)*128+d0] = make_float4(cm[m][0]*rad4.x, cm[m][1]*rad4.y,
                                                    cm[m][2]*rad4.z, cm[m][3]*rad4.w);
    }
    __syncthreads();   // b1: msg ready, hsum/wigA dead

    // issue next edge's global loads (latency hides under GEMM3)
    {
      int s = ei[e_next], d = ei[EE+e_next];
      const float4* hs4 = (const float4*)(h + (size_t)s*LL*CC);
      const float4* hd4 = (const float4*)(h + (size_t)d*LL*CC);
      const float*  we  = wig_g + (size_t)e_next*625;
      float4 a, bb;
      a=hs4[t];     bb=hd4[t];     ph0=make_float4(a.x+bb.x,a.y+bb.y,a.z+bb.z,a.w+bb.w);
      a=hs4[t+256]; bb=hd4[t+256]; ph1=make_float4(a.x+bb.x,a.y+bb.y,a.z+bb.z,a.w+bb.w);
      a=hs4[t+512]; bb=hd4[t+512]; ph2=make_float4(a.x+bb.x,a.y+bb.y,a.z+bb.z,a.w+bb.w);
      if (t<32){ a=hs4[t+768]; bb=hd4[t+768]; ph3=make_float4(a.x+bb.x,a.y+bb.y,a.z+bb.z,a.w+bb.w); }
      pw0 = we[t];
      pw1 = we[t+256];
      if (t<113) pw2 = we[t+512];
    }

    // GEMM3: u[l][c] = sum_k wig[k][l]*msg[k][c]
    {
      float cm[4][4];
      #pragma unroll
      for (int m=0;m<4;m++){ cm[m][0]=0; cm[m][1]=0; cm[m][2]=0; cm[m][3]=0; }
      #pragma unroll 4
      for (int k=0;k<28;k++){
        float4 av = *(const float4*)&wigB[k*32+i0];
        float4 bv = *(const float4*)&msg[k*128+d0];
        fma16(cm, av, bv);
      }
      #pragma unroll
      for (int m=0;m<4;m++)
        *(float4*)&u[(i0+m)*128+d0] = make_float4(cm[m][0], cm[m][1], cm[m][2], cm[m][3]);
    }
    __syncthreads();   // b2: u ready, wigB dead

    {
      { int i2=t;      *(float4*)&hsum[(i2>>5)*128 + (i2&31)*4] = ph0; }
      { int i2=t+256;  *(float4*)&hsum[(i2>>5)*128 + (i2&31)*4] = ph1; }
      { int i2=t+512;  *(float4*)&hsum[(i2>>5)*128 + (i2&31)*4] = ph2; }
      if (t<32){ int i2=t+768; *(float4*)&hsum[(i2>>5)*128 + (i2&31)*4] = ph3; }
      { int i=t;     int r=i/25, c=i-25*r; wigA[c*32+r]=pw0; wigB[r*32+c]=pw0; }
      { int i=t+256; int r=i/25, c=i-25*r; wigA[c*32+r]=pw1; wigB[r*32+c]=pw1; }
      if (t<113){ int i=t+512; int r=i/25, c=i-25*r; wigA[c*32+r]=pw2; wigB[r*32+c]=pw2; }
    }

    // U update: U[l][j] += alpha[e][rt] * u[l][d0+j]
    #pragma unroll
    for (int l=0;l<25;l++){
      float4 uv = *(const float4*)&u[l*128 + d0];
      U[l][0]+=alf*uv.x; U[l][1]+=alf*uv.y; U[l][2]+=alf*uv.z; U[l][3]+=alf*uv.w;
    }
    e = e_next;
    __syncthreads();   // b3: staging complete, u dead
  }

  // ---- finale: o[l][hv] = sum_c U[hv>>4][l][c] * Wv[c][hv], chunked 5 l-rows ----
  #pragma unroll
  for (int ch=0; ch<5; ++ch){
    #pragma unroll
    for (int ls=0; ls<5; ++ls)
      *(float4*)&Uc[(rt*5+ls)*128 + d0] =
        make_float4(U[ch*5+ls][0], U[ch*5+ls][1], U[ch*5+ls][2], U[ch*5+ls][3]);
    __syncthreads();
    {
      int col = t & 127;
      int lr  = t >> 7;            // 0 or 1
      int hh  = col >> 4;
      const float* U0 = &Uc[(hh*5 + lr  )*128];
      const float* U1 = &Uc[(hh*5 + lr+2)*128];
      const float* U2 = &Uc[(hh*5 + (lr? 0:4))*128];
      float o0=0, o1=0, o2=0;
      #pragma unroll 8
      for (int c2=0;c2<128;c2++){
        float wv = Wv[c2*128 + col];
        o0 += U0[c2]*wv; o1 += U1[c2]*wv; o2 += U2[c2]*wv;
      }
      msg[(ch*5+lr  )*128 + col] = o0;
      msg[(ch*5+lr+2)*128 + col] = o1;
      if (lr==0) msg[(ch*5+4)*128 + col] = o2;
    }
    __syncthreads();
  }

  // GEMM4: out[i][c'] = sum_d o_full[i][d]*Wo[d][c']; residual into x
  {
    float co[4][4];
    #pragma unroll
    for (int m=0;m<4;m++){ co[m][0]=0; co[m][1]=0; co[m][2]=0; co[m][3]=0; }
    for (int k4=0;k4<CC;k4+=4){
      float4 A0 = *(const float4*)&msg[(i0+0)*128+k4];
      float4 A1 = *(const float4*)&msg[(i0+1)*128+k4];
      float4 A2 = *(const float4*)&msg[(i0+2)*128+k4];
      float4 A3 = *(const float4*)&msg[(i0+3)*128+k4];
      float4 B0 = *(const float4*)&Wo[(k4+0)*CC + d0];
      float4 B1 = *(const float4*)&Wo[(k4+1)*CC + d0];
      float4 B2 = *(const float4*)&Wo[(k4+2)*CC + d0];
      float4 B3 = *(const float4*)&Wo[(k4+3)*CC + d0];
      gemm_step4(co, A0,A1,A2,A3, B0,B1,B2,B3);
    }
    #pragma unroll
    for (int m=0;m<4;m++){
      int i = i0+m;
      if (i < LL){
        float4 xv = *(float4*)&x[(size_t)n*LL*CC + i*CC + d0];
        xv.x += co[m][0]; xv.y += co[m][1]; xv.z += co[m][2]; xv.w += co[m][3];
        *(float4*)&x[(size_t)n*LL*CC + i*CC + d0] = xv;
      }
    }
  }
}

// ---------------- gated FFN (rmsnorm fused) ----------------
__global__ __launch_bounds__(256)
void k_ffn(float* __restrict__ x, const float* __restrict__ gamma,
           const float* __restrict__ Wf1, const float* __restrict__ Wg,
           const float* __restrict__ Wf2){
  __shared__ float xs[LL][CC];
  __shared__ float tT[CC][32];   // hT then hidT
  __shared__ float gs[FF];
  __shared__ float ps[2][CC];
  int t = threadIdx.x, n = blockIdx.x;
  float* xr = x + n*LL*CC;
  {
    float4* xs4 = (float4*)&xs[0][0];
    const float4* x4 = (const float4*)xr;
    for (int i=t;i<LL*CC/4;i+=256) xs4[i]=x4[i];
  }
  __syncthreads();
  int c = t&127, hf = t>>7;
  int r0 = hf?13:0, r1 = hf?LL:13;
  {
    float s=0;
    for (int r=r0;r<r1;r++){ float v=xs[r][c]; s += v*v; }
    ps[hf][c]=s;
  }
  __syncthreads();
  float rn = 1.0f/sqrtf((ps[0][c]+ps[1][c])*(1.0f/(float)LL) + 1e-6f);
  float gm = gamma[c]*rn;
  for (int r=r0;r<r1;r++) tT[c][r] = xs[r][c]*gm;
  if (hf==0){ for (int r=LL;r<32;r++) tT[c][r] = 0.0f; }
  __syncthreads();
  if (t < FF){
    float gv=0;
    for (int k=0;k<CC;k++) gv += tT[k][0]*Wg[k*FF+t];
    gs[t] = silu_f(gv);
  }
  int dt=t&31, rt=t>>5, d0=dt*4, i0=rt*4;
  float cm[4][4];
  #pragma unroll
  for (int m=0;m<4;m++){ cm[m][0]=0; cm[m][1]=0; cm[m][2]=0; cm[m][3]=0; }
  #pragma unroll 4
  for (int k=0;k<CC;k++){
    float4 av = *(const float4*)&tT[k][i0];
    float4 bv = *(const float4*)&Wf1[k*FF+d0];
    fma16(cm, av, bv);
  }
  __syncthreads();
  #pragma unroll
  for (int j=0;j<4;j++){
    float gj = gs[d0+j];
    *(float4*)&tT[d0+j][i0] = make_float4(cm[0][j]*gj, cm[1][j]*gj, cm[2][j]*gj, cm[3][j]*gj);
  }
  __syncthreads();
  float co[4][4];
  #pragma unroll
  for (int m=0;m<4;m++){ co[m][0]=0; co[m][1]=0; co[m][2]=0; co[m][3]=0; }
  #pragma unroll 4
  for (int k=0;k<FF;k++){
    float4 av = *(const float4*)&tT[k][i0];
    float4 bv = *(const float4*)&Wf2[k*CC+d0];
    fma16(co, av, bv);
  }
  #pragma unroll
  for (int m=0;m<4;m++){
    int i=i0+m;
    if (i<LL){
      float4 xv = *(float4*)&xs[i][d0];
      xv.x+=co[m][0]; xv.y+=co[m][1]; xv.z+=co[m][2]; xv.w+=co[m][3];
      *(float4*)&xr[i*CC+d0] = xv;
    }
  }
}

extern "C" void kernel_launch(void* const* d_in, const int* in_sizes, int n_in,
                              void* d_out, int out_size, void* d_ws, size_t ws_size,
                              hipStream_t stream){
  const int*   zn       = (const int*)  d_in[0];
  const float* pos      = (const float*)d_in[1];
  const int*   ei       = (const int*)  d_in[2];
  const float* wig      = (const float*)d_in[3];
  const float* atom_emb = (const float*)d_in[4];
  const float* src_emb  = (const float*)d_in[5];
  const float* dst_emb  = (const float*)d_in[6];
  const float* W_e1     = (const float*)d_in[7];
  const float* W_e2     = (const float*)d_in[8];
  const float* g_attn   = (const float*)d_in[9];
  const float* g_ffn    = (const float*)d_in[10];
  const float* W_rad    = (const float*)d_in[11];
  const float* W_a1     = (const float*)d_in[12];
  const float* w_a2     = (const float*)d_in[13];
  const float* W_val    = (const float*)d_in[14];
  const float* W_out    = (const float*)d_in[15];
  const float* W_f1     = (const float*)d_in[16];
  const float* W_g      = (const float*)d_in[17];
  const float* W_f2     = (const float*)d_in[18];
  float* x = (float*)d_out;

  char* w = (char*)d_ws;
  float* h      = (float*)w;  w += (size_t)NN*LL*CC*4;
  float* rad0   = (float*)w;  w += (size_t)EE*CC*4;
  float* rad1   = (float*)w;  w += (size_t)EE*CC*4;
  float* logits = (float*)w;  w += (size_t)EE*HH*4;
  float* alpha  = (float*)w;  w += (size_t)EE*HH*4;
  int* order    = (int*)w;    w += (size_t)EE*4;
  int* counts   = (int*)w;    w += (size_t)NN*4;
  int* offsets  = (int*)w;    w += (size_t)(NN+4)*4;
  int* cursor   = (int*)w;    w += (size_t)NN*4;
  float* embw   = (float*)w;  w += (size_t)2*90*CC*4;

  hipMemsetAsync(counts, 0, NN*4, stream);
  hipMemsetAsync(cursor, 0, NN*4, stream);
  k_hist   <<<(EE+255)/256,256,0,stream>>>(ei, counts);
  k_scan   <<<1,256,0,stream>>>(counts, offsets);
  k_scatter<<<(EE+255)/256,256,0,stream>>>(ei, offsets, cursor, order);
  k_embmm  <<<90,256,0,stream>>>(src_emb, dst_emb, W_e1, embw);
  k_edge   <<<(EE+WB-1)/WB,256,0,stream>>>(ei, zn, pos, embw, W_e1, W_e2, W_rad, rad0, rad1);
  k_init_x <<<(NN*LL*CC)/256,256,0,stream>>>(zn, atom_emb, x);

  for (int l=0;l<2;l++){
    const float* radl = l? rad1:rad0;
    k_rms    <<<NN,256,0,stream>>>(x, g_attn + l*CC, h);
    k_logits <<<EE/8,256,0,stream>>>(ei, h, radl, wig, W_a1 + l*CC*HH*AA, w_a2 + l*HH*AA, logits);
    k_softmax<<<NN,64,0,stream>>>(logits, order, offsets, alpha);
    k_attn   <<<NN,256,0,stream>>>(ei, h, wig, radl, alpha, W_val + l*CC*HH*VV,
                                   W_out + l*HH*VV*CC, order, offsets, x);
    k_ffn    <<<NN,256,0,stream>>>(x, g_ffn + l*CC, W_f1 + l*CC*FF, W_g + l*CC*FF, W_f2 + l*FF*CC);
  }
}

// Round 7
// 2209.311 us; speedup vs baseline: 26.6672x; 1.0438x over previous
//
#include <hip/hip_runtime.h>
#include <math.h>

#define NN 2500
#define EE 50000
#define CC 128
#define LL 25
#define HH 8
#define AA 64
#define VV 16
#define FF 128
#define NBASIS 600
#define EFD (NBASIS + 2*CC)   // 856
#define WB 32                 // edges per k_edge block
#define WIN 32                // gaussian window width

__device__ __forceinline__ float silu_f(float x){ return x / (1.0f + expf(-x)); }

__device__ __forceinline__ void fma16(float (&cm)[4][4], const float4& av, const float4& bv){
  cm[0][0]+=av.x*bv.x; cm[0][1]+=av.x*bv.y; cm[0][2]+=av.x*bv.z; cm[0][3]+=av.x*bv.w;
  cm[1][0]+=av.y*bv.x; cm[1][1]+=av.y*bv.y; cm[1][2]+=av.y*bv.z; cm[1][3]+=av.y*bv.w;
  cm[2][0]+=av.z*bv.x; cm[2][1]+=av.z*bv.y; cm[2][2]+=av.z*bv.z; cm[2][3]+=av.z*bv.w;
  cm[3][0]+=av.w*bv.x; cm[3][1]+=av.w*bv.y; cm[3][2]+=av.w*bv.z; cm[3][3]+=av.w*bv.w;
}

// one k4-step of a 4x4-tile GEMM with row-major A segments; named locals only
__device__ __forceinline__ void gemm_step4(float (&cm)[4][4],
    const float4& A0, const float4& A1, const float4& A2, const float4& A3,
    const float4& B0, const float4& B1, const float4& B2, const float4& B3){
  fma16(cm, make_float4(A0.x,A1.x,A2.x,A3.x), B0);
  fma16(cm, make_float4(A0.y,A1.y,A2.y,A3.y), B1);
  fma16(cm, make_float4(A0.z,A1.z,A2.z,A3.z), B2);
  fma16(cm, make_float4(A0.w,A1.w,A2.w,A3.w), B3);
}

// ---------------- edge sort by dst (counting sort) ----------------
__global__ void k_hist(const int* __restrict__ ei, int* __restrict__ counts){
  int e = blockIdx.x*256 + threadIdx.x;
  if (e < EE) atomicAdd(&counts[ei[EE+e]], 1);
}

__global__ void k_scan(const int* __restrict__ counts, int* __restrict__ offsets){
  __shared__ int part[256];
  __shared__ int partx[257];
  int t = threadIdx.x;
  const int chunk = (NN + 255)/256;   // 10
  int base = t*chunk;
  int s = 0;
  for (int i=0;i<chunk;i++){ int idx=base+i; if (idx<NN) s += counts[idx]; }
  part[t] = s;
  __syncthreads();
  if (t==0){ int acc=0; for (int i=0;i<256;i++){ partx[i]=acc; acc+=part[i]; } partx[256]=acc; }
  __syncthreads();
  int acc = partx[t];
  for (int i=0;i<chunk;i++){ int idx=base+i; if (idx<NN){ offsets[idx]=acc; acc+=counts[idx]; } }
  if (t==0) offsets[NN] = partx[256];
}

__global__ void k_scatter(const int* __restrict__ ei, const int* __restrict__ offsets,
                          int* __restrict__ cursor, int* __restrict__ order){
  int e = blockIdx.x*256 + threadIdx.x;
  if (e < EE){
    int d = ei[EE+e];
    int p = atomicAdd(&cursor[d], 1);
    order[offsets[d]+p] = e;
  }
}

// ---------------- init x: only l=0 row populated ----------------
__global__ void k_init_x(const int* __restrict__ zn, const float* __restrict__ atom_emb,
                         float* __restrict__ x){
  int idx = blockIdx.x*256 + threadIdx.x;
  int n = idx / (LL*CC);
  int r = idx - n*(LL*CC);
  float v = 0.0f;
  if (r < CC) v = atom_emb[zn[n]*CC + r];
  x[idx] = v;
}

// ---------------- precompute element-embedding @ W_e1 blocks ----------------
__global__ __launch_bounds__(256)
void k_embmm(const float* __restrict__ src_emb, const float* __restrict__ dst_emb,
             const float* __restrict__ W_e1, float* __restrict__ embw){
  int z = blockIdx.x;          // 0..89
  int t = threadIdx.x;
  int c = t & 127, half = t >> 7;
  const float* emb = half ? dst_emb : src_emb;
  const float* W = W_e1 + (size_t)(NBASIS + half*CC)*CC;
  float acc = 0;
  for (int k=0;k<CC;k++) acc += emb[z*CC+k]*W[k*CC+c];
  embw[((size_t)half*90 + z)*CC + c] = acc;
}

// ---------------- edge scalar features -> rad0, rad1 (windowed basis) ----------------
__global__ __launch_bounds__(256)
void k_edge(const int* __restrict__ ei, const int* __restrict__ zn,
            const float* __restrict__ pos, const float* __restrict__ embw,
            const float* __restrict__ W_e1, const float* __restrict__ W_e2,
            const float* __restrict__ W_rad,
            float* __restrict__ rad0, float* __restrict__ rad1){
  __shared__ float bw[WIN*WB];      // bw[kk][eidx]
  __shared__ float ef [WB*CC];
  __shared__ float ef2[WB*CC];
  __shared__ float dL[WB];
  __shared__ int   k0L[WB], zsL[WB], zdL[WB];
  int t = threadIdx.x;
  int e0 = blockIdx.x*WB;
  const float step = 12.0f/599.0f;
  const float coeff = -0.5f/((2.0f*step)*(2.0f*step));

  if (t < WB){
    int e = e0 + t;
    float dd = 1e15f; int zs=0, zd=0;
    if (e < EE){
      int s = ei[e], d2 = ei[EE+e];
      float dx = pos[s*3]-pos[d2*3], dy = pos[s*3+1]-pos[d2*3+1], dz = pos[s*3+2]-pos[d2*3+2];
      dd = sqrtf(dx*dx+dy*dy+dz*dz);
      zs = zn[s]; zd = zn[d2];
    }
    dL[t] = dd;
    int kk0 = (int)floorf(dd/step + 0.5f);
    if (kk0 < 0) kk0 = 0;
    if (kk0 > NBASIS-1) kk0 = NBASIS-1;
    k0L[t] = kk0;
    zsL[t] = zs; zdL[t] = zd;
  }
  __syncthreads();
  {
    int eidx = t & 31, kb = t >> 5;
    float dd = dL[eidx]; int kk0 = k0L[eidx];
    #pragma unroll
    for (int p=0;p<4;p++){
      int kk = kb + p*8;
      int k = kk0 - 15 + kk;
      float b = 0.0f;
      if (k >= 0 && k < NBASIS){ float u = dd - k*step; b = expf(coeff*u*u); }
      bw[kk*WB + eidx] = b;
    }
  }
  __syncthreads();

  // step1: ef = silu(windowed-basis @ W1a + srcW[zs] + dstW[zd]); 16 cols/thread
  {
    int eidx = t >> 3, cg = t & 7;
    int c0 = cg*16;
    int kk0 = k0L[eidx];
    float4 f0 = make_float4(0,0,0,0), f1=f0, f2=f0, f3=f0;
    #pragma unroll 4
    for (int kk=0;kk<WIN;kk++){
      float b = bw[kk*WB + eidx];
      int k = kk0 - 15 + kk;
      k = k < 0 ? 0 : (k > NBASIS-1 ? NBASIS-1 : k);
      const float* wr = &W_e1[(size_t)k*CC + c0];
      float4 w0 = *(const float4*)&wr[0];
      float4 w1 = *(const float4*)&wr[4];
      float4 w2 = *(const float4*)&wr[8];
      float4 w3 = *(const float4*)&wr[12];
      f0.x+=b*w0.x; f0.y+=b*w0.y; f0.z+=b*w0.z; f0.w+=b*w0.w;
      f1.x+=b*w1.x; f1.y+=b*w1.y; f1.z+=b*w1.z; f1.w+=b*w1.w;
      f2.x+=b*w2.x; f2.y+=b*w2.y; f2.z+=b*w2.z; f2.w+=b*w2.w;
      f3.x+=b*w3.x; f3.y+=b*w3.y; f3.z+=b*w3.z; f3.w+=b*w3.w;
    }
    int zs = zsL[eidx], zd = zdL[eidx];
    const float* sw = &embw[(size_t)zs*CC + c0];
    const float* dw = &embw[(size_t)(90+zd)*CC + c0];
    float4 s0=*(const float4*)&sw[0], s1=*(const float4*)&sw[4], s2=*(const float4*)&sw[8], s3=*(const float4*)&sw[12];
    float4 g0=*(const float4*)&dw[0], g1=*(const float4*)&dw[4], g2=*(const float4*)&dw[8], g3=*(const float4*)&dw[12];
    float* er = &ef[eidx*CC + c0];
    *(float4*)&er[0]  = make_float4(silu_f(f0.x+s0.x+g0.x), silu_f(f0.y+s0.y+g0.y), silu_f(f0.z+s0.z+g0.z), silu_f(f0.w+s0.w+g0.w));
    *(float4*)&er[4]  = make_float4(silu_f(f1.x+s1.x+g1.x), silu_f(f1.y+s1.y+g1.y), silu_f(f1.z+s1.z+g1.z), silu_f(f1.w+s1.w+g1.w));
    *(float4*)&er[8]  = make_float4(silu_f(f2.x+s2.x+g2.x), silu_f(f2.y+s2.y+g2.y), silu_f(f2.z+s2.z+g2.z), silu_f(f2.w+s2.w+g2.w));
    *(float4*)&er[12] = make_float4(silu_f(f3.x+s3.x+g3.x), silu_f(f3.y+s3.y+g3.y), silu_f(f3.z+s3.z+g3.z), silu_f(f3.w+s3.w+g3.w));
  }
  __syncthreads();

  int dt = t & 31, rt = t >> 5;
  int d0 = dt*4, m0 = rt*4;

  // step2: ef2 = silu(ef @ W_e2)
  {
    float cm[4][4];
    #pragma unroll
    for (int m=0;m<4;m++){ cm[m][0]=0; cm[m][1]=0; cm[m][2]=0; cm[m][3]=0; }
    for (int k4=0;k4<CC;k4+=4){
      float4 A0 = *(const float4*)&ef[(m0+0)*CC + k4];
      float4 A1 = *(const float4*)&ef[(m0+1)*CC + k4];
      float4 A2 = *(const float4*)&ef[(m0+2)*CC + k4];
      float4 A3 = *(const float4*)&ef[(m0+3)*CC + k4];
      float4 B0 = *(const float4*)&W_e2[(k4+0)*CC + d0];
      float4 B1 = *(const float4*)&W_e2[(k4+1)*CC + d0];
      float4 B2 = *(const float4*)&W_e2[(k4+2)*CC + d0];
      float4 B3 = *(const float4*)&W_e2[(k4+3)*CC + d0];
      gemm_step4(cm, A0,A1,A2,A3, B0,B1,B2,B3);
    }
    #pragma unroll
    for (int m=0;m<4;m++)
      *(float4*)&ef2[(m0+m)*CC + d0] = make_float4(silu_f(cm[m][0]), silu_f(cm[m][1]),
                                                   silu_f(cm[m][2]), silu_f(cm[m][3]));
  }
  __syncthreads();

  // step3: rad_l = ef2 @ W_rad[l], both layers in one pass (shared A reads)
  {
    float c0m[4][4], c1m[4][4];
    #pragma unroll
    for (int m=0;m<4;m++){ c0m[m][0]=0;c0m[m][1]=0;c0m[m][2]=0;c0m[m][3]=0;
                           c1m[m][0]=0;c1m[m][1]=0;c1m[m][2]=0;c1m[m][3]=0; }
    const float* Wr0 = W_rad;
    const float* Wr1 = W_rad + CC*CC;
    for (int k4=0;k4<CC;k4+=4){
      float4 A0 = *(const float4*)&ef2[(m0+0)*CC + k4];
      float4 A1 = *(const float4*)&ef2[(m0+1)*CC + k4];
      float4 A2 = *(const float4*)&ef2[(m0+2)*CC + k4];
      float4 A3 = *(const float4*)&ef2[(m0+3)*CC + k4];
      float4 B0 = *(const float4*)&Wr0[(k4+0)*CC + d0];
      float4 B1 = *(const float4*)&Wr0[(k4+1)*CC + d0];
      float4 B2 = *(const float4*)&Wr0[(k4+2)*CC + d0];
      float4 B3 = *(const float4*)&Wr0[(k4+3)*CC + d0];
      gemm_step4(c0m, A0,A1,A2,A3, B0,B1,B2,B3);
      float4 D0 = *(const float4*)&Wr1[(k4+0)*CC + d0];
      float4 D1 = *(const float4*)&Wr1[(k4+1)*CC + d0];
      float4 D2 = *(const float4*)&Wr1[(k4+2)*CC + d0];
      float4 D3 = *(const float4*)&Wr1[(k4+3)*CC + d0];
      gemm_step4(c1m, A0,A1,A2,A3, D0,D1,D2,D3);
    }
    #pragma unroll
    for (int m=0;m<4;m++){
      int e = e0 + m0 + m;
      if (e < EE){
        *(float4*)&rad0[(size_t)e*CC + d0] = make_float4(c0m[m][0],c0m[m][1],c0m[m][2],c0m[m][3]);
        *(float4*)&rad1[(size_t)e*CC + d0] = make_float4(c1m[m][0],c1m[m][1],c1m[m][2],c1m[m][3]);
      }
    }
  }
}

// ---------------- equivariant RMS norm -> h ----------------
__global__ __launch_bounds__(256)
void k_rms(const float* __restrict__ x, const float* __restrict__ gamma, float* __restrict__ h){
  __shared__ float xs[LL][CC];
  __shared__ float ps[2][CC];
  int t = threadIdx.x, n = blockIdx.x;
  const float* xr = x + n*LL*CC;
  {
    float4* xs4 = (float4*)&xs[0][0];
    const float4* x4 = (const float4*)xr;
    for (int i=t;i<LL*CC/4;i+=256) xs4[i]=x4[i];
  }
  __syncthreads();
  int c = t&127, hf = t>>7;
  int r0 = hf?13:0, r1 = hf?LL:13;
  float s=0;
  for (int r=r0;r<r1;r++){ float v = xs[r][c]; s += v*v; }
  ps[hf][c]=s;
  __syncthreads();
  float rn = 1.0f/sqrtf((ps[0][c]+ps[1][c])*(1.0f/(float)LL) + 1e-6f);
  float g = gamma[c]*rn;
  float* hr = h + n*LL*CC;
  for (int r=r0;r<r1;r++) hr[r*CC+c] = xs[r][c]*g;
}

// ---------------- attention logits ----------------
__global__ __launch_bounds__(256)
void k_logits(const int* __restrict__ ei, const float* __restrict__ h,
              const float* __restrict__ rad, const float* __restrict__ wig,
              const float* __restrict__ Wa1, const float* __restrict__ wa2,
              float* __restrict__ logits){
  __shared__ float w0[8][LL];
  __shared__ float m0[8][CC];
  __shared__ float aS[8][HH*AA];
  int t = threadIdx.x;
  int e0 = blockIdx.x*8;
  for (int i=t;i<8*LL;i+=256){
    int eidx = i/LL, j = i - eidx*LL;
    w0[eidx][j] = wig[(e0+eidx)*625 + j];
  }
  __syncthreads();
  {
    int c = t&127, eg = t>>7;
    for (int j=0;j<4;j++){
      int e = e0 + eg*4 + j;
      int s = ei[e], d = ei[EE+e];
      const float* hs = h + s*LL*CC + c;
      const float* hd = h + d*LL*CC + c;
      float acc = 0;
      #pragma unroll
      for (int r=0;r<LL;r++) acc += w0[eg*4+j][r]*(hs[r*CC]+hd[r*CC]);
      m0[eg*4+j][c] = acc*rad[e*CC+c];
    }
  }
  __syncthreads();
  float accA[16];
  #pragma unroll
  for (int i=0;i<16;i++) accA[i]=0;
  for (int k=0;k<CC;k++){
    float wv0 = Wa1[k*512 + t];
    float wv1 = Wa1[k*512 + 256 + t];
    #pragma unroll
    for (int e=0;e<8;e++){
      float mv = m0[e][k];
      accA[e*2]   += mv*wv0;
      accA[e*2+1] += mv*wv1;
    }
  }
  #pragma unroll
  for (int e=0;e<8;e++){ aS[e][t]=silu_f(accA[e*2]); aS[e][256+t]=silu_f(accA[e*2+1]); }
  __syncthreads();
  if (t < 64){
    int eidx = t>>3, hh2 = t&7;
    float lg = 0;
    #pragma unroll
    for (int a=0;a<AA;a++) lg += aS[eidx][hh2*AA+a]*wa2[hh2*AA+a];
    logits[(e0+eidx)*HH + hh2] = lg;
  }
}

// ---------------- per-dst softmax (one wave, 8 sub-lanes per head) ----------------
__global__ void k_softmax(const float* __restrict__ logits, const int* __restrict__ order,
                          const int* __restrict__ offsets, float* __restrict__ alpha){
  int n = blockIdx.x, t = threadIdx.x;
  int head = t & 7, sub = t >> 3;
  int b = offsets[n], cnt = offsets[n+1]-b;
  float m = -1e30f;
  for (int i=sub;i<cnt;i+=8) m = fmaxf(m, logits[order[b+i]*HH + head]);
  m = fmaxf(m, __shfl_xor(m, 8));
  m = fmaxf(m, __shfl_xor(m, 16));
  m = fmaxf(m, __shfl_xor(m, 32));
  float z = 0;
  for (int i=sub;i<cnt;i+=8) z += expf(logits[order[b+i]*HH + head] - m);
  z += __shfl_xor(z, 8);
  z += __shfl_xor(z, 16);
  z += __shfl_xor(z, 32);
  float inv = 1.0f/(z + 1e-9f);
  for (int i=sub;i<cnt;i+=8){
    int e = order[b+i];
    alpha[e*HH+head] = expf(logits[e*HH+head]-m)*inv;
  }
}

// ---------------- heavy attention: one block per destination node ----------------
// Per-head W_val/W_out hoist (round 4). This round: conflict-free LDS strides,
// K=25 loops (no pad rows), 49184 B LDS -> 3 blocks/CU, rad/alpha prefetch.
__global__ __launch_bounds__(256,2)
void k_attn(const int* __restrict__ ei, const float* __restrict__ h,
            const float* __restrict__ wig_g, const float* __restrict__ rad,
            const float* __restrict__ alpha,
            const float* __restrict__ Wv, const float* __restrict__ Wo,
            const int* __restrict__ order, const int* __restrict__ offsets,
            float* __restrict__ x){
  __shared__ __align__(16) float smem[12296];   // 49184 B -> 3 blocks/CU
  float* wigA = smem;          // [25][36]  wigA[k*36+i] = wig[i][k], pads zero
  float* wigB = smem + 900;    // [25][36]  wigB[k*36+l] = wig[k][l], pads zero
  float* hsum = smem + 1800;   // [25][128]
  float* msg  = smem + 5000;   // [32][128] rows>=25 compute to exact zeros
  float* u    = smem + 9096;   // [25][128] masked stores
  float* Uc   = smem;          // finale alias [8][4][132] = 4224 (< 5000)

  int n = blockIdx.x;
  int b = offsets[n];
  int cnt = offsets[n+1]-b;
  if (cnt == 0) return;
  int t = threadIdx.x;
  int dt = t & 31, rt = t >> 5;
  int d0 = dt*4, i0 = rt*4;

  float U[25][4];
  #pragma unroll
  for (int l=0;l<25;l++){ U[l][0]=0;U[l][1]=0;U[l][2]=0;U[l][3]=0; }

  // zero wig arrays once (scatter only covers 625 of each 900)
  for (int i=t;i<1800;i+=256) smem[i]=0.0f;

  int e = order[b];
  float4 ph0=make_float4(0,0,0,0), ph1=ph0, ph2=ph0, ph3=ph0;
  float pw0=0, pw1=0, pw2=0;
  float4 prad; float pal;
  {
    int s = ei[e], d = ei[EE+e];
    const float4* hs4 = (const float4*)(h + (size_t)s*LL*CC);
    const float4* hd4 = (const float4*)(h + (size_t)d*LL*CC);
    const float*  we  = wig_g + (size_t)e*625;
    float4 a, bb;
    a=hs4[t];     bb=hd4[t];     ph0=make_float4(a.x+bb.x,a.y+bb.y,a.z+bb.z,a.w+bb.w);
    a=hs4[t+256]; bb=hd4[t+256]; ph1=make_float4(a.x+bb.x,a.y+bb.y,a.z+bb.z,a.w+bb.w);
    a=hs4[t+512]; bb=hd4[t+512]; ph2=make_float4(a.x+bb.x,a.y+bb.y,a.z+bb.z,a.w+bb.w);
    if (t<32){ a=hs4[t+768]; bb=hd4[t+768]; ph3=make_float4(a.x+bb.x,a.y+bb.y,a.z+bb.z,a.w+bb.w); }
    pw0 = we[t];
    pw1 = we[t+256];
    if (t<113) pw2 = we[t+512];
    prad = *(const float4*)&rad[(size_t)e*CC + d0];
    pal  = alpha[(size_t)e*HH + rt];
  }
  __syncthreads();   // zero-init visible
  {
    { int i2=t;      *(float4*)&hsum[(i2>>5)*128 + (i2&31)*4] = ph0; }
    { int i2=t+256;  *(float4*)&hsum[(i2>>5)*128 + (i2&31)*4] = ph1; }
    { int i2=t+512;  *(float4*)&hsum[(i2>>5)*128 + (i2&31)*4] = ph2; }
    if (t<32){ int i2=t+768; *(float4*)&hsum[(i2>>5)*128 + (i2&31)*4] = ph3; }
    { int i=t;     int r=i/25, c=i-25*r; wigA[c*36+r]=pw0; wigB[r*36+c]=pw0; }
    { int i=t+256; int r=i/25, c=i-25*r; wigA[c*36+r]=pw1; wigB[r*36+c]=pw1; }
    if (t<113){ int i=t+512; int r=i/25, c=i-25*r; wigA[c*36+r]=pw2; wigB[r*36+c]=pw2; }
  }
  __syncthreads();

  for (int idx=0; idx<cnt; ++idx){
    float4 rad4 = prad;
    float  alf  = pal;
    int e_next = (idx+1<cnt) ? order[b+idx+1] : e;

    // GEMM1: msg[i][c] = (sum_k wig[i][k]*hsum[k][c]) * rad[c]; K=25
    {
      float cm[4][4];
      #pragma unroll
      for (int m=0;m<4;m++){ cm[m][0]=0; cm[m][1]=0; cm[m][2]=0; cm[m][3]=0; }
      #pragma unroll 5
      for (int k=0;k<25;k++){
        float4 av = *(const float4*)&wigA[k*36+i0];
        float4 bv = *(const float4*)&hsum[k*128+d0];
        fma16(cm, av, bv);
      }
      #pragma unroll
      for (int m=0;m<4;m++)
        *(float4*)&msg[(i0+m)*128+d0] = make_float4(cm[m][0]*rad4.x, cm[m][1]*rad4.y,
                                                    cm[m][2]*rad4.z, cm[m][3]*rad4.w);
    }
    __syncthreads();   // b1: msg ready, hsum/wigA dead

    // issue next edge's global loads (latency hides under GEMM3)
    {
      int s = ei[e_next], d = ei[EE+e_next];
      const float4* hs4 = (const float4*)(h + (size_t)s*LL*CC);
      const float4* hd4 = (const float4*)(h + (size_t)d*LL*CC);
      const float*  we  = wig_g + (size_t)e_next*625;
      float4 a, bb;
      a=hs4[t];     bb=hd4[t];     ph0=make_float4(a.x+bb.x,a.y+bb.y,a.z+bb.z,a.w+bb.w);
      a=hs4[t+256]; bb=hd4[t+256]; ph1=make_float4(a.x+bb.x,a.y+bb.y,a.z+bb.z,a.w+bb.w);
      a=hs4[t+512]; bb=hd4[t+512]; ph2=make_float4(a.x+bb.x,a.y+bb.y,a.z+bb.z,a.w+bb.w);
      if (t<32){ a=hs4[t+768]; bb=hd4[t+768]; ph3=make_float4(a.x+bb.x,a.y+bb.y,a.z+bb.z,a.w+bb.w); }
      pw0 = we[t];
      pw1 = we[t+256];
      if (t<113) pw2 = we[t+512];
      prad = *(const float4*)&rad[(size_t)e_next*CC + d0];
      pal  = alpha[(size_t)e_next*HH + rt];
    }

    // GEMM3: u[l][c] = sum_k wig[k][l]*msg[k][c]; K=25; masked store
    {
      float cm[4][4];
      #pragma unroll
      for (int m=0;m<4;m++){ cm[m][0]=0; cm[m][1]=0; cm[m][2]=0; cm[m][3]=0; }
      #pragma unroll 5
      for (int k=0;k<25;k++){
        float4 av = *(const float4*)&wigB[k*36+i0];
        float4 bv = *(const float4*)&msg[k*128+d0];
        fma16(cm, av, bv);
      }
      #pragma unroll
      for (int m=0;m<4;m++){
        int i = i0+m;
        if (i < 25)
          *(float4*)&u[i*128+d0] = make_float4(cm[m][0], cm[m][1], cm[m][2], cm[m][3]);
      }
    }
    __syncthreads();   // b2: u ready, wigB dead

    // retire staging (hsum/wig dead)
    {
      { int i2=t;      *(float4*)&hsum[(i2>>5)*128 + (i2&31)*4] = ph0; }
      { int i2=t+256;  *(float4*)&hsum[(i2>>5)*128 + (i2&31)*4] = ph1; }
      { int i2=t+512;  *(float4*)&hsum[(i2>>5)*128 + (i2&31)*4] = ph2; }
      if (t<32){ int i2=t+768; *(float4*)&hsum[(i2>>5)*128 + (i2&31)*4] = ph3; }
      { int i=t;     int r=i/25, c=i-25*r; wigA[c*36+r]=pw0; wigB[r*36+c]=pw0; }
      { int i=t+256; int r=i/25, c=i-25*r; wigA[c*36+r]=pw1; wigB[r*36+c]=pw1; }
      if (t<113){ int i=t+512; int r=i/25, c=i-25*r; wigA[c*36+r]=pw2; wigB[r*36+c]=pw2; }
    }

    // U update: U[l][j] += alpha[e][rt] * u[l][d0+j]
    #pragma unroll
    for (int l=0;l<25;l++){
      float4 uv = *(const float4*)&u[l*128 + d0];
      U[l][0]+=alf*uv.x; U[l][1]+=alf*uv.y; U[l][2]+=alf*uv.z; U[l][3]+=alf*uv.w;
    }
    e = e_next;
    __syncthreads();   // b3: staging complete, u dead
  }

  // ---- finale: o[l][hv] = sum_c U[hv>>4][l][c] * Wv[c][hv], 7 chunks of 4 rows ----
  // Uc stride 132: bank = (4*row + c2) % 32 -> 8 concurrent rows hit 8 distinct banks.
  #pragma unroll
  for (int ch=0; ch<7; ++ch){
    #pragma unroll
    for (int ls=0; ls<4; ++ls){
      int r = ch*4+ls; if (r > 24) r = 24;   // compile-time after unroll
      *(float4*)&Uc[(rt*4+ls)*132 + d0] = make_float4(U[r][0],U[r][1],U[r][2],U[r][3]);
    }
    __syncthreads();
    {
      int col = t & 127;
      int lr  = t >> 7;            // 0 or 1
      int hh  = col >> 4;
      const float* U0 = &Uc[(hh*4 + lr  )*132];
      const float* U1 = &Uc[(hh*4 + lr+2)*132];
      float o0=0, o1=0;
      #pragma unroll 8
      for (int c2=0;c2<128;c2++){
        float wv = Wv[c2*128 + col];
        o0 += U0[c2]*wv; o1 += U1[c2]*wv;
      }
      int r0w = ch*4+lr, r1w = ch*4+lr+2;
      if (r0w < 25) msg[r0w*128 + col] = o0;
      if (r1w < 25) msg[r1w*128 + col] = o1;
    }
    __syncthreads();
  }

  // GEMM4: out[i][c'] = sum_d o_full[i][d]*Wo[d][c']; residual into x
  // (msg rows >=25 are exact zeros from last GEMM1 -> safe unmasked A-reads)
  {
    float co[4][4];
    #pragma unroll
    for (int m=0;m<4;m++){ co[m][0]=0; co[m][1]=0; co[m][2]=0; co[m][3]=0; }
    for (int k4=0;k4<CC;k4+=4){
      float4 A0 = *(const float4*)&msg[(i0+0)*128+k4];
      float4 A1 = *(const float4*)&msg[(i0+1)*128+k4];
      float4 A2 = *(const float4*)&msg[(i0+2)*128+k4];
      float4 A3 = *(const float4*)&msg[(i0+3)*128+k4];
      float4 B0 = *(const float4*)&Wo[(k4+0)*CC + d0];
      float4 B1 = *(const float4*)&Wo[(k4+1)*CC + d0];
      float4 B2 = *(const float4*)&Wo[(k4+2)*CC + d0];
      float4 B3 = *(const float4*)&Wo[(k4+3)*CC + d0];
      gemm_step4(co, A0,A1,A2,A3, B0,B1,B2,B3);
    }
    #pragma unroll
    for (int m=0;m<4;m++){
      int i = i0+m;
      if (i < LL){
        float4 xv = *(float4*)&x[(size_t)n*LL*CC + i*CC + d0];
        xv.x += co[m][0]; xv.y += co[m][1]; xv.z += co[m][2]; xv.w += co[m][3];
        *(float4*)&x[(size_t)n*LL*CC + i*CC + d0] = xv;
      }
    }
  }
}

// ---------------- gated FFN (rmsnorm fused) ----------------
__global__ __launch_bounds__(256)
void k_ffn(float* __restrict__ x, const float* __restrict__ gamma,
           const float* __restrict__ Wf1, const float* __restrict__ Wg,
           const float* __restrict__ Wf2){
  __shared__ float xs[LL][CC];
  __shared__ float tT[CC][32];   // hT then hidT
  __shared__ float gs[FF];
  __shared__ float ps[2][CC];
  int t = threadIdx.x, n = blockIdx.x;
  float* xr = x + n*LL*CC;
  {
    float4* xs4 = (float4*)&xs[0][0];
    const float4* x4 = (const float4*)xr;
    for (int i=t;i<LL*CC/4;i+=256) xs4[i]=x4[i];
  }
  __syncthreads();
  int c = t&127, hf = t>>7;
  int r0 = hf?13:0, r1 = hf?LL:13;
  {
    float s=0;
    for (int r=r0;r<r1;r++){ float v=xs[r][c]; s += v*v; }
    ps[hf][c]=s;
  }
  __syncthreads();
  float rn = 1.0f/sqrtf((ps[0][c]+ps[1][c])*(1.0f/(float)LL) + 1e-6f);
  float gm = gamma[c]*rn;
  for (int r=r0;r<r1;r++) tT[c][r] = xs[r][c]*gm;
  if (hf==0){ for (int r=LL;r<32;r++) tT[c][r] = 0.0f; }
  __syncthreads();
  if (t < FF){
    float gv=0;
    for (int k=0;k<CC;k++) gv += tT[k][0]*Wg[k*FF+t];
    gs[t] = silu_f(gv);
  }
  int dt=t&31, rt=t>>5, d0=dt*4, i0=rt*4;
  float cm[4][4];
  #pragma unroll
  for (int m=0;m<4;m++){ cm[m][0]=0; cm[m][1]=0; cm[m][2]=0; cm[m][3]=0; }
  #pragma unroll 4
  for (int k=0;k<CC;k++){
    float4 av = *(const float4*)&tT[k][i0];
    float4 bv = *(const float4*)&Wf1[k*FF+d0];
    fma16(cm, av, bv);
  }
  __syncthreads();
  #pragma unroll
  for (int j=0;j<4;j++){
    float gj = gs[d0+j];
    *(float4*)&tT[d0+j][i0] = make_float4(cm[0][j]*gj, cm[1][j]*gj, cm[2][j]*gj, cm[3][j]*gj);
  }
  __syncthreads();
  float co[4][4];
  #pragma unroll
  for (int m=0;m<4;m++){ co[m][0]=0; co[m][1]=0; co[m][2]=0; co[m][3]=0; }
  #pragma unroll 4
  for (int k=0;k<FF;k++){
    float4 av = *(const float4*)&tT[k][i0];
    float4 bv = *(const float4*)&Wf2[k*CC+d0];
    fma16(co, av, bv);
  }
  #pragma unroll
  for (int m=0;m<4;m++){
    int i=i0+m;
    if (i<LL){
      float4 xv = *(float4*)&xs[i][d0];
      xv.x+=co[m][0]; xv.y+=co[m][1]; xv.z+=co[m][2]; xv.w+=co[m][3];
      *(float4*)&xr[i*CC+d0] = xv;
    }
  }
}

extern "C" void kernel_launch(void* const* d_in, const int* in_sizes, int n_in,
                              void* d_out, int out_size, void* d_ws, size_t ws_size,
                              hipStream_t stream){
  const int*   zn       = (const int*)  d_in[0];
  const float* pos      = (const float*)d_in[1];
  const int*   ei       = (const int*)  d_in[2];
  const float* wig      = (const float*)d_in[3];
  const float* atom_emb = (const float*)d_in[4];
  const float* src_emb  = (const float*)d_in[5];
  const float* dst_emb  = (const float*)d_in[6];
  const float* W_e1     = (const float*)d_in[7];
  const float* W_e2     = (const float*)d_in[8];
  const float* g_attn   = (const float*)d_in[9];
  const float* g_ffn    = (const float*)d_in[10];
  const float* W_rad    = (const float*)d_in[11];
  const float* W_a1     = (const float*)d_in[12];
  const float* w_a2     = (const float*)d_in[13];
  const float* W_val    = (const float*)d_in[14];
  const float* W_out    = (const float*)d_in[15];
  const float* W_f1     = (const float*)d_in[16];
  const float* W_g      = (const float*)d_in[17];
  const float* W_f2     = (const float*)d_in[18];
  float* x = (float*)d_out;

  char* w = (char*)d_ws;
  float* h      = (float*)w;  w += (size_t)NN*LL*CC*4;
  float* rad0   = (float*)w;  w += (size_t)EE*CC*4;
  float* rad1   = (float*)w;  w += (size_t)EE*CC*4;
  float* logits = (float*)w;  w += (size_t)EE*HH*4;
  float* alpha  = (float*)w;  w += (size_t)EE*HH*4;
  int* order    = (int*)w;    w += (size_t)EE*4;
  int* counts   = (int*)w;    w += (size_t)NN*4;
  int* offsets  = (int*)w;    w += (size_t)(NN+4)*4;
  int* cursor   = (int*)w;    w += (size_t)NN*4;
  float* embw   = (float*)w;  w += (size_t)2*90*CC*4;

  hipMemsetAsync(counts, 0, NN*4, stream);
  hipMemsetAsync(cursor, 0, NN*4, stream);
  k_hist   <<<(EE+255)/256,256,0,stream>>>(ei, counts);
  k_scan   <<<1,256,0,stream>>>(counts, offsets);
  k_scatter<<<(EE+255)/256,256,0,stream>>>(ei, offsets, cursor, order);
  k_embmm  <<<90,256,0,stream>>>(src_emb, dst_emb, W_e1, embw);
  k_edge   <<<(EE+WB-1)/WB,256,0,stream>>>(ei, zn, pos, embw, W_e1, W_e2, W_rad, rad0, rad1);
  k_init_x <<<(NN*LL*CC)/256,256,0,stream>>>(zn, atom_emb, x);

  for (int l=0;l<2;l++){
    const float* radl = l? rad1:rad0;
    k_rms    <<<NN,256,0,stream>>>(x, g_attn + l*CC, h);
    k_logits <<<EE/8,256,0,stream>>>(ei, h, radl, wig, W_a1 + l*CC*HH*AA, w_a2 + l*HH*AA, logits);
    k_softmax<<<NN,64,0,stream>>>(logits, order, offsets, alpha);
    k_attn   <<<NN,256,0,stream>>>(ei, h, wig, radl, alpha, W_val + l*CC*HH*VV,
                                   W_out + l*HH*VV*CC, order, offsets, x);
    k_ffn    <<<NN,256,0,stream>>>(x, g_ffn + l*CC, W_f1 + l*CC*FF, W_g + l*CC*FF, W_f2 + l*FF*CC);
  }
}